// Round 1
// baseline (1429.982 us; speedup 1.0000x reference)
//
#include <hip/hip_runtime.h>
#include <stdint.h>

// ---------------------------------------------------------------------------
// JambaMambaMixer: B=1, L=2048, H=4096, D=8192, N=16, K=4, R=256
// Pipeline: in_proj GEMM -> causal depthwise conv+SiLU -> x_proj GEMM ->
//           RMSNorms -> dt_proj GEMM (+softplus) -> selective scan ->
//           skip + gate -> out_proj GEMM
// GEMMs in bf16 MFMA (fp32 accum); scan/norms in fp32.
// ---------------------------------------------------------------------------

#define LSEQ 2048
#define HDIM 4096
#define DDIM 8192
#define NST  16
#define RRANK 256
#define NPAD 384   // R + 2N = 288 padded to 3*128

typedef __bf16 bf16x8 __attribute__((ext_vector_type(8)));
typedef float  f32x4  __attribute__((ext_vector_type(4)));

__device__ __forceinline__ ushort f2b(float f) {
  uint32_t x = __float_as_uint(f);
  x += 0x7FFFu + ((x >> 16) & 1u);           // RNE
  return (ushort)(x >> 16);
}
__device__ __forceinline__ float b2f(ushort u) {
  return __uint_as_float(((uint32_t)u) << 16);
}

__device__ __forceinline__ void gload_lds16(const ushort* g, ushort* l) {
  __builtin_amdgcn_global_load_lds(
      (const __attribute__((address_space(1))) void*)g,
      (__attribute__((address_space(3))) void*)l, 16, 0, 0);
}

// ---------------- f32 -> bf16 conversion (8 elems/thread) ------------------
__global__ __launch_bounds__(256) void cvt_kernel(const float* __restrict__ s,
                                                  ushort* __restrict__ d,
                                                  size_t n8) {
  size_t i = (size_t)blockIdx.x * 256 + threadIdx.x;
  if (i >= n8) return;
  const float4* sp = (const float4*)s;
  float4 a = sp[2 * i], b = sp[2 * i + 1];
  union { ushort us[8]; uint4 v; } u;
  u.us[0] = f2b(a.x); u.us[1] = f2b(a.y); u.us[2] = f2b(a.z); u.us[3] = f2b(a.w);
  u.us[4] = f2b(b.x); u.us[5] = f2b(b.y); u.us[6] = f2b(b.z); u.us[7] = f2b(b.w);
  ((uint4*)d)[i] = u.v;
}

// ---------------- bf16 NT GEMM: C[M,N] = A[M,K] * Bw[N,K]^T ----------------
// 128x128 tile, BK=64, 256 threads (4 waves, 2x2), mfma_f32_16x16x32_bf16.
// LDS staged via global_load_lds width 16 with XOR slot swizzle applied to
// the GLOBAL source (LDS dest must stay linear) and the matching XOR on the
// ds_read side (rule #21: both-sides-or-neither).
// EPI: 0 = plain f32 store, 1 = softplus(acc + bias[col]).
template <int EPI>
__global__ __launch_bounds__(256) void gemm_nt(
    const ushort* __restrict__ A, const ushort* __restrict__ Bw,
    float* __restrict__ C, int M, int N, int K,
    const float* __restrict__ bias) {
  __shared__ __align__(16) ushort As[128 * 64];
  __shared__ __align__(16) ushort Bs[128 * 64];
  const int tid  = threadIdx.x;
  const int lane = tid & 63;
  const int wid  = tid >> 6;
  const int wr = wid >> 1, wc = wid & 1;
  const int m0 = blockIdx.y * 128, n0 = blockIdx.x * 128;
  const int rr0 = tid >> 3;      // staging row within 32-row group
  const int sl  = tid & 7;       // staging 16B slot within 128B row
  const int lrow = lane & 15;
  const int lks  = lane >> 4;

  f32x4 acc[4][4] = {};

  for (int k0 = 0; k0 < K; k0 += 64) {
#pragma unroll
    for (int i = 0; i < 4; ++i) {
      int rr  = i * 32 + rr0;
      int ksl = sl ^ (rr & 7);   // pre-swizzled source slot
      const ushort* ga = A  + (size_t)(m0 + rr) * K + k0 + ksl * 8;
      const ushort* gb = Bw + (size_t)(n0 + rr) * K + k0 + ksl * 8;
      ushort* la = As + (i * 256 + (wid << 6)) * 8;   // wave-uniform base
      ushort* lb = Bs + (i * 256 + (wid << 6)) * 8;
      gload_lds16(ga, la);
      gload_lds16(gb, lb);
    }
    __syncthreads();   // compiler drains vmcnt(0) before barrier
#pragma unroll
    for (int kc = 0; kc < 2; ++kc) {
      bf16x8 av[4], bv[4];
#pragma unroll
      for (int mi = 0; mi < 4; ++mi) {
        int row = wr * 64 + mi * 16 + lrow;
        int ks  = kc * 4 + lks;
        av[mi] = *(const bf16x8*)(As + row * 64 + ((ks ^ (row & 7)) << 3));
      }
#pragma unroll
      for (int ni = 0; ni < 4; ++ni) {
        int row = wc * 64 + ni * 16 + lrow;
        int ks  = kc * 4 + lks;
        bv[ni] = *(const bf16x8*)(Bs + row * 64 + ((ks ^ (row & 7)) << 3));
      }
#pragma unroll
      for (int mi = 0; mi < 4; ++mi)
#pragma unroll
        for (int ni = 0; ni < 4; ++ni)
          acc[mi][ni] = __builtin_amdgcn_mfma_f32_16x16x32_bf16(
              av[mi], bv[ni], acc[mi][ni], 0, 0, 0);
    }
    __syncthreads();
  }

  // epilogue: C/D layout col=lane&15, row=(lane>>4)*4+q  [m89-verified]
#pragma unroll
  for (int mi = 0; mi < 4; ++mi) {
    int row0 = m0 + wr * 64 + mi * 16 + (lks << 2);
#pragma unroll
    for (int ni = 0; ni < 4; ++ni) {
      int col = n0 + wc * 64 + ni * 16 + lrow;
      float bcol = 0.f;
      if (EPI == 1) bcol = bias[col];
#pragma unroll
      for (int q = 0; q < 4; ++q) {
        float v = acc[mi][ni][q];
        if (EPI == 1) {
          v += bcol;
          v = (v > 20.f) ? v : log1pf(__expf(v));   // softplus
        }
        C[(size_t)(row0 + q) * N + col] = v;
      }
    }
  }
}

// ---------------- causal depthwise conv1d (K=4) + bias + SiLU --------------
// in: proj[:, 0:8192] (row stride 16384), out: u_conv bf16 [L, D]
__global__ __launch_bounds__(256) void conv_silu_kernel(
    const float* __restrict__ proj, const float* __restrict__ cw,
    const float* __restrict__ cb, ushort* __restrict__ uc) {
  int d = blockIdx.x * 256 + threadIdx.x;
  int l = blockIdx.y;
  float4 w4 = ((const float4*)cw)[d];
  float wa[4] = {w4.x, w4.y, w4.z, w4.w};
  float s = cb[d];
#pragma unroll
  for (int j = 0; j < 4; ++j) {
    int li = l - 3 + j;
    if (li >= 0) s += wa[j] * proj[(size_t)li * 16384 + d];
  }
  float o = s / (1.f + __expf(-s));
  uc[(size_t)l * DDIM + d] = f2b(o);
}

// ---------------- RMSNorms for dt (256), B (16), C (16) --------------------
__global__ __launch_bounds__(64) void norms_kernel(
    const float* __restrict__ ssmp, const float* __restrict__ dtw,
    const float* __restrict__ bw, const float* __restrict__ cwn,
    ushort* __restrict__ dtn, float* __restrict__ Bn, float* __restrict__ Cn) {
  int l = blockIdx.x, lane = threadIdx.x;
  const float* row = ssmp + (size_t)l * NPAD;
  float4 v = ((const float4*)row)[lane];
  float va[4] = {v.x, v.y, v.z, v.w};
  float ss = va[0]*va[0] + va[1]*va[1] + va[2]*va[2] + va[3]*va[3];
#pragma unroll
  for (int m = 32; m >= 1; m >>= 1) ss += __shfl_xor(ss, m);
  float rs = rsqrtf(ss * (1.f / 256.f) + 1e-6f);
  float4 w = ((const float4*)dtw)[lane];
  float wa[4] = {w.x, w.y, w.z, w.w};
  union { ushort us[4]; uint2 v2; } o;
#pragma unroll
  for (int j = 0; j < 4; ++j) o.us[j] = f2b(va[j] * rs * wa[j]);
  ((uint2*)(dtn + (size_t)l * 256))[lane] = o.v2;

  int g = lane & 15;
  float bv = row[256 + g], cv = row[272 + g];
  float bs = bv * bv, cs = cv * cv;
#pragma unroll
  for (int m = 8; m >= 1; m >>= 1) {
    bs += __shfl_xor(bs, m);
    cs += __shfl_xor(cs, m);
  }
  if (lane < 16) {
    Bn[(size_t)l * NST + lane] = bv * rsqrtf(bs * (1.f / 16.f) + 1e-6f) * bw[lane];
    Cn[(size_t)l * NST + lane] = cv * rsqrtf(cs * (1.f / 16.f) + 1e-6f) * cwn[lane];
  }
}

// ---------------- selective scan -------------------------------------------
// Block: 256 threads = 16 channels x 16 states; lane (d,n); state in reg.
// LDS-chunked (CL=128) staging; 16-lane shfl_xor reduce for y = sum_n st*C.
// ybuf has row stride 16384 (reuses proj's u-half).
__global__ __launch_bounds__(256) void scan_kernel(
    const float* __restrict__ delta, const ushort* __restrict__ uc,
    const float* __restrict__ Bn, const float* __restrict__ Cn,
    const float* __restrict__ Am, float* __restrict__ ybuf) {
  const int CL = 128;
  __shared__ float2 sDU[128 * 16];
  __shared__ float2 sBC[128 * 16];
  __shared__ float  sY[128 * 16];
  int tid = threadIdx.x;
  int d0 = blockIdx.x * 16;
  int ch = tid >> 4, n = tid & 15;
  float Adn = Am[(size_t)(d0 + ch) * NST + n];
  float st = 0.f;
  for (int l0 = 0; l0 < LSEQ; l0 += CL) {
    __syncthreads();  // prev write-out done before restage
    for (int idx = tid; idx < CL * 16; idx += 256) {
      int l = idx >> 4, c = idx & 15;
      size_t gi = (size_t)(l0 + l) * DDIM + d0 + c;
      sDU[idx] = make_float2(delta[gi], b2f(uc[gi]));
      sBC[idx] = make_float2(Bn[(size_t)(l0 + l) * NST + c],
                             Cn[(size_t)(l0 + l) * NST + c]);
    }
    __syncthreads();
    for (int l = 0; l < CL; ++l) {
      float2 du = sDU[l * 16 + ch];   // (delta, u) broadcast across 16 lanes
      float2 bc = sBC[l * 16 + n];    // (B, C)
      float dA = __expf(du.x * Adn);
      st = fmaf(dA, st, (du.x * du.y) * bc.x);
      float p = st * bc.y;
      p += __shfl_xor(p, 1);
      p += __shfl_xor(p, 2);
      p += __shfl_xor(p, 4);
      p += __shfl_xor(p, 8);
      if (n == 0) sY[l * 16 + ch] = p;
    }
    __syncthreads();
    for (int idx = tid; idx < CL * 16; idx += 256) {
      int l = idx >> 4, c = idx & 15;
      ybuf[(size_t)(l0 + l) * 16384 + d0 + c] = sY[idx];
    }
  }
}

// ---------------- skip + gate: yg = (y + u*D) * silu(gate) -----------------
__global__ __launch_bounds__(256) void gate_kernel(
    const float* __restrict__ projY, const ushort* __restrict__ uc,
    const float* __restrict__ Dp, ushort* __restrict__ yg) {
  int d = blockIdx.x * 256 + threadIdx.x;
  int l = blockIdx.y;
  float y = projY[(size_t)l * 16384 + d];
  float u = b2f(uc[(size_t)l * DDIM + d]);
  float g = projY[(size_t)l * 16384 + DDIM + d];
  float o = (y + u * Dp[d]) * (g / (1.f + __expf(-g)));
  yg[(size_t)l * DDIM + d] = f2b(o);
}

// ---------------------------------------------------------------------------
extern "C" void kernel_launch(void* const* d_in, const int* in_sizes, int n_in,
                              void* d_out, int out_size, void* d_ws, size_t ws_size,
                              hipStream_t stream) {
  (void)in_sizes; (void)n_in; (void)out_size; (void)ws_size;
  const float* hs   = (const float*)d_in[0];
  const float* W_in = (const float*)d_in[1];
  const float* cw   = (const float*)d_in[2];
  const float* cb   = (const float*)d_in[3];
  const float* Wx   = (const float*)d_in[4];
  const float* dtw  = (const float*)d_in[5];
  const float* bw   = (const float*)d_in[6];
  const float* cwn  = (const float*)d_in[7];
  const float* Wdt  = (const float*)d_in[8];
  const float* dtb  = (const float*)d_in[9];
  const float* Am   = (const float*)d_in[10];
  const float* Dp   = (const float*)d_in[11];
  const float* Wout = (const float*)d_in[12];
  float* out = (float*)d_out;

  char* ws = (char*)d_ws;
  // region A (128MB): W_in_bf16 for GEMM1; afterwards reused as
  //   delta f32 [0,64MB) + W_out_bf16 [64MB,128MB)
  ushort* win_b  = (ushort*)(ws + 0);
  float*  delta  = (float*) (ws + 0);
  ushort* wout_b = (ushort*)(ws + 67108864);
  ushort* hs_b   = (ushort*)(ws + 134217728);   // 16MB
  ushort* wxp_b  = (ushort*)(ws + 150994944);   // 6MB  (padded 384 rows)
  ushort* wdt_b  = (ushort*)(ws + 157286400);   // 4MB
  float*  proj   = (float*) (ws + 161480704);   // 128MB; u-half reused as ybuf
  ushort* ucv    = (ushort*)(ws + 295698432);   // 32MB
  float*  ssmp   = (float*) (ws + 329252864);   // 3MB  [2048,384]
  ushort* dtn    = (ushort*)(ws + 332398592);   // 1MB
  float*  Bn     = (float*) (ws + 333447168);
  float*  Cn     = (float*) (ws + 333578240);
  ushort* yg     = (ushort*)(ws + 333709312);   // 32MB; end = 367,263,744

  // f32 -> bf16 conversions
  cvt_kernel<<<67108864 / 2048, 256, 0, stream>>>(W_in, win_b, 67108864 / 8);
  cvt_kernel<<<8388608 / 2048, 256, 0, stream>>>(hs, hs_b, 8388608 / 8);
  cvt_kernel<<<2359296 / 2048, 256, 0, stream>>>(Wx, wxp_b, 2359296 / 8);
  hipMemsetAsync(ws + 150994944 + 4718592, 0, 1572864, stream);  // zero pad rows 288..383
  cvt_kernel<<<2097152 / 2048, 256, 0, stream>>>(Wdt, wdt_b, 2097152 / 8);

  // 1) in_proj: proj[2048,16384] = hs_b @ win_b^T
  gemm_nt<0><<<dim3(128, 16), 256, 0, stream>>>(hs_b, win_b, proj,
                                                2048, 16384, 4096, nullptr);
  // W_out conversion into region A second half (GEMM1 finished reading it)
  cvt_kernel<<<33554432 / 2048, 256, 0, stream>>>(Wout, wout_b, 33554432 / 8);

  // 2) causal conv + SiLU -> u_conv bf16
  conv_silu_kernel<<<dim3(32, 2048), 256, 0, stream>>>(proj, cw, cb, ucv);

  // 3) x_proj: ssmp[2048,384] = ucv @ wxp^T (padded N)
  gemm_nt<0><<<dim3(3, 16), 256, 0, stream>>>(ucv, wxp_b, ssmp,
                                              2048, NPAD, 8192, nullptr);

  // 4) RMSNorms
  norms_kernel<<<2048, 64, 0, stream>>>(ssmp, dtw, bw, cwn, dtn, Bn, Cn);

  // 5) dt_proj + softplus: delta[2048,8192]
  gemm_nt<1><<<dim3(64, 16), 256, 0, stream>>>(dtn, wdt_b, delta,
                                               2048, 8192, 256, dtb);

  // 6) selective scan -> ybuf (= proj u-half, row stride 16384)
  scan_kernel<<<512, 256, 0, stream>>>(delta, ucv, Bn, Cn, Am, proj);

  // 7) skip + gate -> yg bf16
  gate_kernel<<<dim3(32, 2048), 256, 0, stream>>>(proj, ucv, Dp, yg);

  // 8) out_proj -> d_out f32 [2048,4096]
  gemm_nt<0><<<dim3(32, 16), 256, 0, stream>>>(yg, wout_b, out,
                                               2048, 4096, 8192, nullptr);
}

// Round 2
// 962.880 us; speedup vs baseline: 1.4851x; 1.4851x over previous
//
#include <hip/hip_runtime.h>
#include <stdint.h>

// ---------------------------------------------------------------------------
// JambaMambaMixer: B=1, L=2048, H=4096, D=8192, N=16, K=4, R=256
// R1: chunked-parallel selective scan (lane-per-channel, state in VGPRs,
//     gate fused into phase3), split-K for the narrow x_proj GEMM.
// ---------------------------------------------------------------------------

#define LSEQ 2048
#define HDIM 4096
#define DDIM 8192
#define NST  16
#define NPAD 384   // R + 2N = 288 padded to 3*128
#define NC   16    // scan chunks
#define CLEN 128   // LSEQ / NC

typedef __bf16 bf16x8 __attribute__((ext_vector_type(8)));
typedef float  f32x4  __attribute__((ext_vector_type(4)));

__device__ __forceinline__ ushort f2b(float f) {
  uint32_t x = __float_as_uint(f);
  x += 0x7FFFu + ((x >> 16) & 1u);           // RNE
  return (ushort)(x >> 16);
}
__device__ __forceinline__ float b2f(ushort u) {
  return __uint_as_float(((uint32_t)u) << 16);
}

__device__ __forceinline__ void gload_lds16(const ushort* g, ushort* l) {
  __builtin_amdgcn_global_load_lds(
      (const __attribute__((address_space(1))) void*)g,
      (__attribute__((address_space(3))) void*)l, 16, 0, 0);
}

// ---------------- f32 -> bf16 conversion (8 elems/thread) ------------------
__global__ __launch_bounds__(256) void cvt_kernel(const float* __restrict__ s,
                                                  ushort* __restrict__ d,
                                                  size_t n8) {
  size_t i = (size_t)blockIdx.x * 256 + threadIdx.x;
  if (i >= n8) return;
  const float4* sp = (const float4*)s;
  float4 a = sp[2 * i], b = sp[2 * i + 1];
  union { ushort us[8]; uint4 v; } u;
  u.us[0] = f2b(a.x); u.us[1] = f2b(a.y); u.us[2] = f2b(a.z); u.us[3] = f2b(a.w);
  u.us[4] = f2b(b.x); u.us[5] = f2b(b.y); u.us[6] = f2b(b.z); u.us[7] = f2b(b.w);
  ((uint4*)d)[i] = u.v;
}

// ---------------- bf16 NT GEMM: C[M,N] = A[M,K] * Bw[N,K]^T ----------------
// 128x128 tile, BK=64, 256 threads (4 waves, 2x2), mfma_f32_16x16x32_bf16.
// XOR slot swizzle applied to the GLOBAL source (LDS dest linear) + matching
// XOR on the ds_read side. ldk = row stride of A/Bw; Kc = K-range per z-slice
// (grid.z slices write to C + z*M*N). EPI: 0 = f32 store, 1 = softplus+bias.
template <int EPI>
__global__ __launch_bounds__(256) void gemm_nt(
    const ushort* __restrict__ A, const ushort* __restrict__ Bw,
    float* __restrict__ C, int M, int N, int ldk, int Kc,
    const float* __restrict__ bias) {
  __shared__ __align__(16) ushort As[128 * 64];
  __shared__ __align__(16) ushort Bs[128 * 64];
  const int tid  = threadIdx.x;
  const int lane = tid & 63;
  const int wid  = tid >> 6;
  const int wr = wid >> 1, wc = wid & 1;
  const int m0 = blockIdx.y * 128, n0 = blockIdx.x * 128;
  const int kbeg = blockIdx.z * Kc;
  C += (size_t)blockIdx.z * M * N;
  const int rr0 = tid >> 3;      // staging row within 32-row group
  const int sl  = tid & 7;       // staging 16B slot within 128B row
  const int lrow = lane & 15;
  const int lks  = lane >> 4;

  f32x4 acc[4][4] = {};

  for (int k0 = kbeg; k0 < kbeg + Kc; k0 += 64) {
#pragma unroll
    for (int i = 0; i < 4; ++i) {
      int rr  = i * 32 + rr0;
      int ksl = sl ^ (rr & 7);   // pre-swizzled source slot
      const ushort* ga = A  + (size_t)(m0 + rr) * ldk + k0 + ksl * 8;
      const ushort* gb = Bw + (size_t)(n0 + rr) * ldk + k0 + ksl * 8;
      ushort* la = As + (i * 256 + (wid << 6)) * 8;   // wave-uniform base
      ushort* lb = Bs + (i * 256 + (wid << 6)) * 8;
      gload_lds16(ga, la);
      gload_lds16(gb, lb);
    }
    __syncthreads();
#pragma unroll
    for (int kc = 0; kc < 2; ++kc) {
      bf16x8 av[4], bv[4];
#pragma unroll
      for (int mi = 0; mi < 4; ++mi) {
        int row = wr * 64 + mi * 16 + lrow;
        int ks  = kc * 4 + lks;
        av[mi] = *(const bf16x8*)(As + row * 64 + ((ks ^ (row & 7)) << 3));
      }
#pragma unroll
      for (int ni = 0; ni < 4; ++ni) {
        int row = wc * 64 + ni * 16 + lrow;
        int ks  = kc * 4 + lks;
        bv[ni] = *(const bf16x8*)(Bs + row * 64 + ((ks ^ (row & 7)) << 3));
      }
#pragma unroll
      for (int mi = 0; mi < 4; ++mi)
#pragma unroll
        for (int ni = 0; ni < 4; ++ni)
          acc[mi][ni] = __builtin_amdgcn_mfma_f32_16x16x32_bf16(
              av[mi], bv[ni], acc[mi][ni], 0, 0, 0);
    }
    __syncthreads();
  }

  // epilogue: C/D layout col=lane&15, row=(lane>>4)*4+q
#pragma unroll
  for (int mi = 0; mi < 4; ++mi) {
    int row0 = m0 + wr * 64 + mi * 16 + (lks << 2);
#pragma unroll
    for (int ni = 0; ni < 4; ++ni) {
      int col = n0 + wc * 64 + ni * 16 + lrow;
      float bcol = 0.f;
      if (EPI == 1) bcol = bias[col];
#pragma unroll
      for (int q = 0; q < 4; ++q) {
        float v = acc[mi][ni][q];
        if (EPI == 1) {
          v += bcol;
          v = (v > 20.f) ? v : log1pf(__expf(v));   // softplus
        }
        C[(size_t)(row0 + q) * N + col] = v;
      }
    }
  }
}

// ---------------- split-K partial reduce: ssmp = sum_z Cp[z] ----------------
__global__ __launch_bounds__(256) void reduce8_kernel(
    const float* __restrict__ Cp, float* __restrict__ out) {
  size_t i = (size_t)blockIdx.x * 256 + threadIdx.x;   // 2048*384
  const size_t MN = (size_t)LSEQ * NPAD;
  float s = 0.f;
#pragma unroll
  for (int z = 0; z < 8; ++z) s += Cp[z * MN + i];
  out[i] = s;
}

// ---------------- causal depthwise conv1d (K=4) + bias + SiLU --------------
__global__ __launch_bounds__(256) void conv_silu_kernel(
    const float* __restrict__ ubuf, const float* __restrict__ cw,
    const float* __restrict__ cb, ushort* __restrict__ uc) {
  int d = blockIdx.x * 256 + threadIdx.x;
  int l = blockIdx.y;
  float4 w4 = ((const float4*)cw)[d];
  float wa[4] = {w4.x, w4.y, w4.z, w4.w};
  float s = cb[d];
#pragma unroll
  for (int j = 0; j < 4; ++j) {
    int li = l - 3 + j;
    if (li >= 0) s += wa[j] * ubuf[(size_t)li * DDIM + d];
  }
  float o = s / (1.f + __expf(-s));
  uc[(size_t)l * DDIM + d] = f2b(o);
}

// ---------------- RMSNorms for dt (256), B (16), C (16) --------------------
__global__ __launch_bounds__(64) void norms_kernel(
    const float* __restrict__ ssmp, const float* __restrict__ dtw,
    const float* __restrict__ bw, const float* __restrict__ cwn,
    ushort* __restrict__ dtn, float* __restrict__ Bn, float* __restrict__ Cn) {
  int l = blockIdx.x, lane = threadIdx.x;
  const float* row = ssmp + (size_t)l * NPAD;
  float4 v = ((const float4*)row)[lane];
  float va[4] = {v.x, v.y, v.z, v.w};
  float ss = va[0]*va[0] + va[1]*va[1] + va[2]*va[2] + va[3]*va[3];
#pragma unroll
  for (int m = 32; m >= 1; m >>= 1) ss += __shfl_xor(ss, m);
  float rs = rsqrtf(ss * (1.f / 256.f) + 1e-6f);
  float4 w = ((const float4*)dtw)[lane];
  float wa[4] = {w.x, w.y, w.z, w.w};
  union { ushort us[4]; uint2 v2; } o;
#pragma unroll
  for (int j = 0; j < 4; ++j) o.us[j] = f2b(va[j] * rs * wa[j]);
  ((uint2*)(dtn + (size_t)l * 256))[lane] = o.v2;

  int g = lane & 15;
  float bv = row[256 + g], cv = row[272 + g];
  float bs = bv * bv, cs = cv * cv;
#pragma unroll
  for (int m = 8; m >= 1; m >>= 1) {
    bs += __shfl_xor(bs, m);
    cs += __shfl_xor(cs, m);
  }
  if (lane < 16) {
    Bn[(size_t)l * NST + lane] = bv * rsqrtf(bs * (1.f / 16.f) + 1e-6f) * bw[lane];
    Cn[(size_t)l * NST + lane] = cv * rsqrtf(cs * (1.f / 16.f) + 1e-6f) * cwn[lane];
  }
}

// ---------------- selective scan, chunked over L ----------------------------
// Lane = one channel d; st[16] in VGPRs; no cross-lane ops.
// Phase 1: per chunk c, compute S = local scan end-state (init 0) and
//          P = exp(A * sum delta) = decay product over the chunk.
// Phase 2: serial prefix over the NC chunks -> init state per chunk (in Pbuf).
// Phase 3: replay chunk from init, y = sum_n st*C, fused skip+gate -> yg bf16.

__global__ __launch_bounds__(256) void scan_phase1(
    const float* __restrict__ delta, const ushort* __restrict__ uc,
    const float* __restrict__ Bn, const float* __restrict__ Am,
    float* __restrict__ Sbuf, float* __restrict__ Pbuf) {
  __shared__ float sB[CLEN * NST];
  const int tid = threadIdx.x;
  const int d = blockIdx.x * 256 + tid;
  const int c = blockIdx.y, l0 = c * CLEN;
  {
    const float4* bsrc = (const float4*)(Bn + (size_t)l0 * NST);
    float4* bdst = (float4*)sB;
    for (int i = tid; i < CLEN * NST / 4; i += 256) bdst[i] = bsrc[i];
  }
  __syncthreads();
  float A[16];
#pragma unroll
  for (int j = 0; j < 4; ++j) {
    float4 a4 = ((const float4*)(Am + (size_t)d * NST))[j];
    A[4*j] = a4.x; A[4*j+1] = a4.y; A[4*j+2] = a4.z; A[4*j+3] = a4.w;
  }
  float st[16] = {};
  float sd = 0.f;
  const size_t base = (size_t)l0 * DDIM + d;
  float dx0 = delta[base],            dx1 = delta[base + DDIM];
  float ux0 = b2f(uc[base]),          ux1 = b2f(uc[base + DDIM]);
  for (int l = 0; l < CLEN; l += 2) {
    int lp = (l + 2 < CLEN) ? l + 2 : CLEN - 2;   // clamped prefetch
    float dxn0 = delta[base + (size_t)lp * DDIM];
    float dxn1 = delta[base + (size_t)(lp + 1) * DDIM];
    float uxn0 = b2f(uc[base + (size_t)lp * DDIM]);
    float uxn1 = b2f(uc[base + (size_t)(lp + 1) * DDIM]);
    sd += dx0;
    float dxu = dx0 * ux0;
#pragma unroll
    for (int n = 0; n < 16; ++n)
      st[n] = fmaf(__expf(dx0 * A[n]), st[n], dxu * sB[l * NST + n]);
    sd += dx1;
    dxu = dx1 * ux1;
#pragma unroll
    for (int n = 0; n < 16; ++n)
      st[n] = fmaf(__expf(dx1 * A[n]), st[n], dxu * sB[(l + 1) * NST + n]);
    dx0 = dxn0; dx1 = dxn1; ux0 = uxn0; ux1 = uxn1;
  }
  float4* Sd = (float4*)(Sbuf + ((size_t)c * DDIM + d) * NST);
  float4* Pd = (float4*)(Pbuf + ((size_t)c * DDIM + d) * NST);
#pragma unroll
  for (int j = 0; j < 4; ++j) {
    Sd[j] = make_float4(st[4*j], st[4*j+1], st[4*j+2], st[4*j+3]);
    Pd[j] = make_float4(__expf(A[4*j] * sd),   __expf(A[4*j+1] * sd),
                        __expf(A[4*j+2] * sd), __expf(A[4*j+3] * sd));
  }
}

__global__ __launch_bounds__(256) void scan_phase2(
    const float* __restrict__ Sbuf, float* __restrict__ Pbuf) {
  size_t t = (size_t)blockIdx.x * 256 + threadIdx.x;   // over D*16
  const size_t stride = (size_t)DDIM * NST;
  float s = 0.f;
  for (int c = 0; c < NC; ++c) {
    float P = Pbuf[c * stride + t];
    float S = Sbuf[c * stride + t];
    Pbuf[c * stride + t] = s;        // init state for chunk c
    s = fmaf(P, s, S);
  }
}

__global__ __launch_bounds__(256) void scan_phase3(
    const float* __restrict__ delta, const ushort* __restrict__ uc,
    const float* __restrict__ Bn, const float* __restrict__ Cn,
    const float* __restrict__ Am, const float* __restrict__ Ibuf,
    const float* __restrict__ gbuf, const float* __restrict__ Dp,
    ushort* __restrict__ yg) {
  __shared__ float sB[CLEN * NST];
  __shared__ float sC[CLEN * NST];
  const int tid = threadIdx.x;
  const int d = blockIdx.x * 256 + tid;
  const int c = blockIdx.y, l0 = c * CLEN;
  {
    const float4* bsrc = (const float4*)(Bn + (size_t)l0 * NST);
    const float4* csrc = (const float4*)(Cn + (size_t)l0 * NST);
    float4* bdst = (float4*)sB;
    float4* cdst = (float4*)sC;
    for (int i = tid; i < CLEN * NST / 4; i += 256) {
      bdst[i] = bsrc[i];
      cdst[i] = csrc[i];
    }
  }
  __syncthreads();
  float A[16], st[16];
#pragma unroll
  for (int j = 0; j < 4; ++j) {
    float4 a4 = ((const float4*)(Am + (size_t)d * NST))[j];
    A[4*j] = a4.x; A[4*j+1] = a4.y; A[4*j+2] = a4.z; A[4*j+3] = a4.w;
    float4 s4 = ((const float4*)(Ibuf + ((size_t)c * DDIM + d) * NST))[j];
    st[4*j] = s4.x; st[4*j+1] = s4.y; st[4*j+2] = s4.z; st[4*j+3] = s4.w;
  }
  const float Dpd = Dp[d];
  const size_t base = (size_t)l0 * DDIM + d;
  float dx0 = delta[base],   dx1 = delta[base + DDIM];
  float ux0 = b2f(uc[base]), ux1 = b2f(uc[base + DDIM]);
  float g0  = gbuf[base],    g1  = gbuf[base + DDIM];
  for (int l = 0; l < CLEN; l += 2) {
    int lp = (l + 2 < CLEN) ? l + 2 : CLEN - 2;
    float dxn0 = delta[base + (size_t)lp * DDIM];
    float dxn1 = delta[base + (size_t)(lp + 1) * DDIM];
    float uxn0 = b2f(uc[base + (size_t)lp * DDIM]);
    float uxn1 = b2f(uc[base + (size_t)(lp + 1) * DDIM]);
    float gn0  = gbuf[base + (size_t)lp * DDIM];
    float gn1  = gbuf[base + (size_t)(lp + 1) * DDIM];
    {
      float dxu = dx0 * ux0, y0 = 0.f, y1 = 0.f;
#pragma unroll
      for (int n = 0; n < 16; n += 2) {
        st[n]   = fmaf(__expf(dx0 * A[n]),   st[n],   dxu * sB[l * NST + n]);
        st[n+1] = fmaf(__expf(dx0 * A[n+1]), st[n+1], dxu * sB[l * NST + n+1]);
        y0 = fmaf(st[n],   sC[l * NST + n],   y0);
        y1 = fmaf(st[n+1], sC[l * NST + n+1], y1);
      }
      float o = (y0 + y1 + ux0 * Dpd) * (g0 / (1.f + __expf(-g0)));
      yg[base + (size_t)l * DDIM] = f2b(o);
    }
    {
      float dxu = dx1 * ux1, y0 = 0.f, y1 = 0.f;
#pragma unroll
      for (int n = 0; n < 16; n += 2) {
        st[n]   = fmaf(__expf(dx1 * A[n]),   st[n],   dxu * sB[(l+1) * NST + n]);
        st[n+1] = fmaf(__expf(dx1 * A[n+1]), st[n+1], dxu * sB[(l+1) * NST + n+1]);
        y0 = fmaf(st[n],   sC[(l+1) * NST + n],   y0);
        y1 = fmaf(st[n+1], sC[(l+1) * NST + n+1], y1);
      }
      float o = (y0 + y1 + ux1 * Dpd) * (g1 / (1.f + __expf(-g1)));
      yg[base + (size_t)(l + 1) * DDIM] = f2b(o);
    }
    dx0 = dxn0; dx1 = dxn1; ux0 = uxn0; ux1 = uxn1; g0 = gn0; g1 = gn1;
  }
}

// ---------------------------------------------------------------------------
extern "C" void kernel_launch(void* const* d_in, const int* in_sizes, int n_in,
                              void* d_out, int out_size, void* d_ws, size_t ws_size,
                              hipStream_t stream) {
  (void)in_sizes; (void)n_in; (void)out_size; (void)ws_size;
  const float* hs   = (const float*)d_in[0];
  const float* W_in = (const float*)d_in[1];
  const float* cw   = (const float*)d_in[2];
  const float* cb   = (const float*)d_in[3];
  const float* Wx   = (const float*)d_in[4];
  const float* dtw  = (const float*)d_in[5];
  const float* bw   = (const float*)d_in[6];
  const float* cwn  = (const float*)d_in[7];
  const float* Wdt  = (const float*)d_in[8];
  const float* dtb  = (const float*)d_in[9];
  const float* Am   = (const float*)d_in[10];
  const float* Dp   = (const float*)d_in[11];
  const float* Wout = (const float*)d_in[12];
  float* out = (float*)d_out;

  char* ws = (char*)d_ws;
  const size_t MB = 1ull << 20;
  // region A (128MB): win_b for GEMM1; after GEMM1: delta (64MB) + wout_b (64MB)
  ushort* win_b  = (ushort*)(ws);
  float*  delta  = (float*) (ws);
  ushort* wout_b = (ushort*)(ws + 64 * MB);
  // region B (64MB): ubuf for conv; after conv: Cp (24MB) + Sbuf (8MB) + Pbuf (8MB)
  float*  ubuf   = (float*) (ws + 128 * MB);
  float*  Cp     = (float*) (ws + 128 * MB);
  float*  Sbuf   = (float*) (ws + 152 * MB);
  float*  Pbuf   = (float*) (ws + 160 * MB);
  float*  gbuf   = (float*) (ws + 192 * MB);          // 64MB
  ushort* hs_b   = (ushort*)(ws + 256 * MB);          // 16MB
  ushort* wxp_b  = (ushort*)(ws + 272 * MB);          // 6MB (384 rows, pad zeroed)
  ushort* wdt_b  = (ushort*)(ws + 278 * MB);          // 4MB
  ushort* ucv    = (ushort*)(ws + 282 * MB);          // 32MB
  float*  ssmp   = (float*) (ws + 314 * MB);          // 3MB [2048,384]
  ushort* dtn    = (ushort*)(ws + 317 * MB);          // 1MB
  float*  Bn     = (float*) (ws + 318 * MB);          // 128KB
  float*  Cn     = (float*) (ws + 318 * MB + 131072); // 128KB
  ushort* yg     = (ushort*)(ws + 319 * MB);          // 32MB; end 351MB

  // f32 -> bf16 conversions
  cvt_kernel<<<67108864 / 2048, 256, 0, stream>>>(W_in, win_b, 67108864 / 8);
  cvt_kernel<<<8388608 / 2048, 256, 0, stream>>>(hs, hs_b, 8388608 / 8);
  cvt_kernel<<<2359296 / 2048, 256, 0, stream>>>(Wx, wxp_b, 2359296 / 8);
  hipMemsetAsync((char*)wxp_b + 4718592, 0, 1572864, stream);  // pad rows 288..383
  cvt_kernel<<<2097152 / 2048, 256, 0, stream>>>(Wdt, wdt_b, 2097152 / 8);

  // 1) in_proj split into u and gate halves
  gemm_nt<0><<<dim3(64, 16), 256, 0, stream>>>(hs_b, win_b, ubuf,
                                               2048, DDIM, 4096, 4096, nullptr);
  gemm_nt<0><<<dim3(64, 16), 256, 0, stream>>>(hs_b, win_b + (size_t)DDIM * 4096,
                                               gbuf, 2048, DDIM, 4096, 4096, nullptr);
  // W_out conversion into region A second half (GEMM1 finished reading win_b)
  cvt_kernel<<<33554432 / 2048, 256, 0, stream>>>(Wout, wout_b, 33554432 / 8);

  // 2) causal conv + SiLU -> u_conv bf16 (ubuf dead afterwards)
  conv_silu_kernel<<<dim3(32, 2048), 256, 0, stream>>>(ubuf, cw, cb, ucv);

  // 3) x_proj, split-K x8 over K=8192 -> partials, then reduce
  gemm_nt<0><<<dim3(3, 16, 8), 256, 0, stream>>>(ucv, wxp_b, Cp,
                                                 2048, NPAD, 8192, 1024, nullptr);
  reduce8_kernel<<<3072, 256, 0, stream>>>(Cp, ssmp);

  // 4) RMSNorms
  norms_kernel<<<2048, 64, 0, stream>>>(ssmp, dtw, bw, cwn, dtn, Bn, Cn);

  // 5) dt_proj + softplus: delta[2048,8192] (region A first half)
  gemm_nt<1><<<dim3(64, 16), 256, 0, stream>>>(dtn, wdt_b, delta,
                                               2048, DDIM, 256, 256, dtb);

  // 6) chunked selective scan; phase3 fuses skip+gate -> yg bf16
  scan_phase1<<<dim3(32, NC), 256, 0, stream>>>(delta, ucv, Bn, Am, Sbuf, Pbuf);
  scan_phase2<<<512, 256, 0, stream>>>(Sbuf, Pbuf);
  scan_phase3<<<dim3(32, NC), 256, 0, stream>>>(delta, ucv, Bn, Cn, Am, Pbuf,
                                                gbuf, Dp, yg);

  // 7) out_proj -> d_out f32 [2048,4096]
  gemm_nt<0><<<dim3(32, 16), 256, 0, stream>>>(yg, wout_b, out,
                                               2048, 4096, 8192, 8192, nullptr);
}

// Round 3
// 893.151 us; speedup vs baseline: 1.6011x; 1.0781x over previous
//
#include <hip/hip_runtime.h>
#include <stdint.h>

// ---------------------------------------------------------------------------
// JambaMambaMixer: B=1, L=2048, H=4096, D=8192, N=16, K=4, R=256
// R2: 8-phase 256x256 deep-pipelined GEMM (counted vmcnt(6), per-phase
//     stage, 16-MFMA clusters, setprio) for in_proj / out_proj.
// ---------------------------------------------------------------------------

#define LSEQ 2048
#define HDIM 4096
#define DDIM 8192
#define NST  16
#define NPAD 384   // R + 2N = 288 padded to 3*128
#define NC   16    // scan chunks
#define CLEN 128   // LSEQ / NC

typedef __bf16 bf16x8 __attribute__((ext_vector_type(8)));
typedef float  f32x4  __attribute__((ext_vector_type(4)));

__device__ __forceinline__ ushort f2b(float f) {
  uint32_t x = __float_as_uint(f);
  x += 0x7FFFu + ((x >> 16) & 1u);           // RNE
  return (ushort)(x >> 16);
}
__device__ __forceinline__ float b2f(ushort u) {
  return __uint_as_float(((uint32_t)u) << 16);
}

__device__ __forceinline__ void gload_lds16(const ushort* g, ushort* l) {
  __builtin_amdgcn_global_load_lds(
      (const __attribute__((address_space(1))) void*)g,
      (__attribute__((address_space(3))) void*)l, 16, 0, 0);
}

// ---------------- f32 -> bf16 conversion (8 elems/thread) ------------------
__global__ __launch_bounds__(256) void cvt_kernel(const float* __restrict__ s,
                                                  ushort* __restrict__ d,
                                                  size_t n8) {
  size_t i = (size_t)blockIdx.x * 256 + threadIdx.x;
  if (i >= n8) return;
  const float4* sp = (const float4*)s;
  float4 a = sp[2 * i], b = sp[2 * i + 1];
  union { ushort us[8]; uint4 v; } u;
  u.us[0] = f2b(a.x); u.us[1] = f2b(a.y); u.us[2] = f2b(a.z); u.us[3] = f2b(a.w);
  u.us[4] = f2b(b.x); u.us[5] = f2b(b.y); u.us[6] = f2b(b.z); u.us[7] = f2b(b.w);
  ((uint4*)d)[i] = u.v;
}

// ======================= 8-phase 256x256 bf16 NT GEMM =======================
// C[M,N] = A[M,K] * Bw[N,K]^T. 512 thr = 8 waves (2m x 4n), per-wave 128x64.
// BK=64, double-buffered 128KiB LDS, per-phase 1 half/quarter-tile stage,
// vmcnt(6) only at phases 4/8, slot^=(row&7) swizzle (src-side + read-side).
__global__ __launch_bounds__(512, 2) void gemm8p(
    const ushort* __restrict__ A, const ushort* __restrict__ Bw,
    float* __restrict__ C, int M, int N, int ldk, int Kc) {
  __shared__ __align__(16) ushort As[2][256 * 64];
  __shared__ __align__(16) ushort Bs[2][256 * 64];
  const int tid  = threadIdx.x;
  const int lane = tid & 63;
  const int w    = tid >> 6;     // wave 0..7
  const int wr   = w >> 2;       // m half 0..1
  const int wc   = w & 3;        // n quarter 0..3

  // XCD-aware block swizzle (nwg % 8 == 0 for all our grids)
  const int nbx = gridDim.x;
  const int nwg = nbx * gridDim.y;
  int bid = blockIdx.y * nbx + blockIdx.x;
  const int cpx = nwg >> 3;
  int swz = (bid & 7) * cpx + (bid >> 3);
  const int m0 = (swz / nbx) * 256, n0 = (swz % nbx) * 256;
  const int kbeg = blockIdx.z * Kc;
  C += (size_t)blockIdx.z * M * N;
  const int NT = Kc >> 6;        // even, >= 2

  // staging constants: 16B slot pre-swizzle (involution)
  const int srck = (lane & 7) ^ ((lane >> 3) & 7);
  const int astripe = w >> 2, awl = w & 3;
  const int arow_st = astripe * 128 + awl * 8 + (lane >> 3);
  const ushort* Abase = A + (size_t)(m0 + arow_st) * ldk + kbeg + srck * 8;
  const int aldsb = (astripe * 128 + awl * 8) * 64;
  const int brow_st = w * 8 + (lane >> 3);
  const ushort* Bbase = Bw + (size_t)(n0 + brow_st) * ldk + kbeg + srck * 8;
  const int bldsb = (w * 8) * 64;

  // read-side constants
  const int lrow = lane & 15;
  const int kch  = lane >> 4;
  const int axor = lrow & 7;

  auto stA = [&](int buf, int kt, int q) {
    gload_lds16(Abase + (size_t)q * 32 * ldk + kt * 64,
                &As[buf][aldsb + q * 32 * 64]);
  };
  auto stB = [&](int buf, int kt, int half, int j) {
    gload_lds16(Bbase + (size_t)(half * 128 + j * 64) * ldk + kt * 64,
                &Bs[buf][bldsb + (half * 128 + j * 64) * 64]);
  };
  auto rdA = [&](int buf, int mi, int sl) -> bf16x8 {
    int arow = wr * 128 + mi * 16 + lrow;
    int s4 = sl * 4 + kch;
    return *(const bf16x8*)&As[buf][arow * 64 + ((s4 ^ axor) << 3)];
  };
  auto rdB = [&](int buf, int ni, int sl) -> bf16x8 {
    int brow = wc * 64 + ni * 16 + lrow;
    int s4 = sl * 4 + kch;
    return *(const bf16x8*)&Bs[buf][brow * 64 + ((s4 ^ axor) << 3)];
  };

  f32x4 acc[8][4] = {};

  // prologue: t0 full (B h0,h1 + A q0..q3), t1 partial (B h0,h1 + A q0,q1)
  stB(0, 0, 0, 0); stB(0, 0, 0, 1); stB(0, 0, 1, 0); stB(0, 0, 1, 1);
  stA(0, 0, 0); stA(0, 0, 1); stA(0, 0, 2); stA(0, 0, 3);
  stB(1, 1, 0, 0); stB(1, 1, 0, 1); stB(1, 1, 1, 0); stB(1, 1, 1, 1);
  stA(1, 1, 0); stA(1, 1, 1);
  asm volatile("s_waitcnt vmcnt(6)" ::: "memory");   // t0 fully landed
  asm volatile("s_barrier" ::: "memory");

#define PHASE(BUF, Q, STAGES)                                                 \
  {                                                                           \
    if (Q == 0) {                                                             \
      _Pragma("unroll") for (int ni = 0; ni < 4; ++ni)                        \
        _Pragma("unroll") for (int sl = 0; sl < 2; ++sl)                      \
          bfr[ni][sl] = rdB(BUF, ni, sl);                                     \
    }                                                                         \
    _Pragma("unroll") for (int m2 = 0; m2 < 2; ++m2)                          \
      _Pragma("unroll") for (int sl = 0; sl < 2; ++sl)                        \
        afr[m2][sl] = rdA(BUF, Q * 2 + m2, sl);                               \
    STAGES;                                                                   \
    asm volatile("s_barrier" ::: "memory");                                   \
    __builtin_amdgcn_s_setprio(1);                                            \
    _Pragma("unroll") for (int sl = 0; sl < 2; ++sl)                          \
      _Pragma("unroll") for (int m2 = 0; m2 < 2; ++m2)                        \
        _Pragma("unroll") for (int ni = 0; ni < 4; ++ni)                      \
          acc[Q * 2 + m2][ni] = __builtin_amdgcn_mfma_f32_16x16x32_bf16(      \
              afr[m2][sl], bfr[ni][sl], acc[Q * 2 + m2][ni], 0, 0, 0);        \
    __builtin_amdgcn_s_setprio(0);                                            \
  }

  for (int t = 0; t < NT; t += 2) {
    const int t2 = (t + 2 < NT) ? t + 2 : 0;   // wrap-guard: valid mem, unread
    const int t3 = (t + 3 < NT) ? t + 3 : 0;
    bf16x8 bfr[4][2], afr[2][2];
    // group 0: tile t in buf0
    PHASE(0, 0, { stA(1, t + 1, 2); stA(1, t + 1, 3); });
    asm volatile("s_barrier" ::: "memory");
    PHASE(0, 1, { stB(0, t2, 0, 0); stB(0, t2, 0, 1); });
    asm volatile("s_barrier" ::: "memory");
    PHASE(0, 2, { stB(0, t2, 1, 0); stB(0, t2, 1, 1); });
    asm volatile("s_barrier" ::: "memory");
    PHASE(0, 3, { stA(0, t2, 0); stA(0, t2, 1); });
    asm volatile("s_waitcnt vmcnt(6)" ::: "memory");
    asm volatile("s_barrier" ::: "memory");
    // group 1: tile t+1 in buf1
    PHASE(1, 0, { stA(0, t2, 2); stA(0, t2, 3); });
    asm volatile("s_barrier" ::: "memory");
    PHASE(1, 1, { stB(1, t3, 0, 0); stB(1, t3, 0, 1); });
    asm volatile("s_barrier" ::: "memory");
    PHASE(1, 2, { stB(1, t3, 1, 0); stB(1, t3, 1, 1); });
    asm volatile("s_barrier" ::: "memory");
    PHASE(1, 3, { stA(1, t3, 0); stA(1, t3, 1); });
    asm volatile("s_waitcnt vmcnt(6)" ::: "memory");
    asm volatile("s_barrier" ::: "memory");
  }
#undef PHASE

  asm volatile("s_waitcnt vmcnt(0)" ::: "memory");   // drain tail stages
  // epilogue: C/D layout col=lane&15, row=(lane>>4)*4+q
#pragma unroll
  for (int mi = 0; mi < 8; ++mi) {
    int row0 = m0 + wr * 128 + mi * 16 + kch * 4;
#pragma unroll
    for (int ni = 0; ni < 4; ++ni) {
      int col = n0 + wc * 64 + ni * 16 + lrow;
#pragma unroll
      for (int q_ = 0; q_ < 4; ++q_)
        C[(size_t)(row0 + q_) * N + col] = acc[mi][ni][q_];
    }
  }
}

// ---------------- 128x128 bf16 NT GEMM (narrow shapes) ----------------------
template <int EPI>
__global__ __launch_bounds__(256) void gemm_nt(
    const ushort* __restrict__ A, const ushort* __restrict__ Bw,
    float* __restrict__ C, int M, int N, int ldk, int Kc,
    const float* __restrict__ bias) {
  __shared__ __align__(16) ushort As[128 * 64];
  __shared__ __align__(16) ushort Bs[128 * 64];
  const int tid  = threadIdx.x;
  const int lane = tid & 63;
  const int wid  = tid >> 6;
  const int wr = wid >> 1, wc = wid & 1;
  const int m0 = blockIdx.y * 128, n0 = blockIdx.x * 128;
  const int kbeg = blockIdx.z * Kc;
  C += (size_t)blockIdx.z * M * N;
  const int rr0 = tid >> 3;
  const int sl  = tid & 7;
  const int lrow = lane & 15;
  const int lks  = lane >> 4;

  f32x4 acc[4][4] = {};

  for (int k0 = kbeg; k0 < kbeg + Kc; k0 += 64) {
#pragma unroll
    for (int i = 0; i < 4; ++i) {
      int rr  = i * 32 + rr0;
      int ksl = sl ^ (rr & 7);
      const ushort* ga = A  + (size_t)(m0 + rr) * ldk + k0 + ksl * 8;
      const ushort* gb = Bw + (size_t)(n0 + rr) * ldk + k0 + ksl * 8;
      ushort* la = As + (i * 256 + (wid << 6)) * 8;
      ushort* lb = Bs + (i * 256 + (wid << 6)) * 8;
      gload_lds16(ga, la);
      gload_lds16(gb, lb);
    }
    __syncthreads();
#pragma unroll
    for (int kc = 0; kc < 2; ++kc) {
      bf16x8 av[4], bv[4];
#pragma unroll
      for (int mi = 0; mi < 4; ++mi) {
        int row = wr * 64 + mi * 16 + lrow;
        int ks  = kc * 4 + lks;
        av[mi] = *(const bf16x8*)(As + row * 64 + ((ks ^ (row & 7)) << 3));
      }
#pragma unroll
      for (int ni = 0; ni < 4; ++ni) {
        int row = wc * 64 + ni * 16 + lrow;
        int ks  = kc * 4 + lks;
        bv[ni] = *(const bf16x8*)(Bs + row * 64 + ((ks ^ (row & 7)) << 3));
      }
#pragma unroll
      for (int mi = 0; mi < 4; ++mi)
#pragma unroll
        for (int ni = 0; ni < 4; ++ni)
          acc[mi][ni] = __builtin_amdgcn_mfma_f32_16x16x32_bf16(
              av[mi], bv[ni], acc[mi][ni], 0, 0, 0);
    }
    __syncthreads();
  }

#pragma unroll
  for (int mi = 0; mi < 4; ++mi) {
    int row0 = m0 + wr * 64 + mi * 16 + (lks << 2);
#pragma unroll
    for (int ni = 0; ni < 4; ++ni) {
      int col = n0 + wc * 64 + ni * 16 + lrow;
      float bcol = 0.f;
      if (EPI == 1) bcol = bias[col];
#pragma unroll
      for (int q = 0; q < 4; ++q) {
        float v = acc[mi][ni][q];
        if (EPI == 1) {
          v += bcol;
          v = (v > 20.f) ? v : log1pf(__expf(v));
        }
        C[(size_t)(row0 + q) * N + col] = v;
      }
    }
  }
}

// ---------------- split-K reduces -------------------------------------------
__global__ __launch_bounds__(256) void reduce8_kernel(
    const float* __restrict__ Cp, float* __restrict__ out) {
  size_t i = (size_t)blockIdx.x * 256 + threadIdx.x;
  const size_t MN = (size_t)LSEQ * NPAD;
  float s = 0.f;
#pragma unroll
  for (int z = 0; z < 8; ++z) s += Cp[z * MN + i];
  out[i] = s;
}

__global__ __launch_bounds__(256) void reduce2_kernel(
    const float* __restrict__ Cp, float* __restrict__ out) {
  size_t i = (size_t)blockIdx.x * 256 + threadIdx.x;
  const size_t MN4 = (size_t)LSEQ * HDIM / 4;
  float4 a = ((const float4*)Cp)[i];
  float4 b = ((const float4*)Cp)[MN4 + i];
  ((float4*)out)[i] = make_float4(a.x + b.x, a.y + b.y, a.z + b.z, a.w + b.w);
}

// ---------------- causal depthwise conv1d (K=4) + bias + SiLU --------------
__global__ __launch_bounds__(256) void conv_silu_kernel(
    const float* __restrict__ ubuf, const float* __restrict__ cw,
    const float* __restrict__ cb, ushort* __restrict__ uc) {
  int d = blockIdx.x * 256 + threadIdx.x;
  int l = blockIdx.y;
  float4 w4 = ((const float4*)cw)[d];
  float wa[4] = {w4.x, w4.y, w4.z, w4.w};
  float s = cb[d];
#pragma unroll
  for (int j = 0; j < 4; ++j) {
    int li = l - 3 + j;
    if (li >= 0) s += wa[j] * ubuf[(size_t)li * DDIM + d];
  }
  float o = s / (1.f + __expf(-s));
  uc[(size_t)l * DDIM + d] = f2b(o);
}

// ---------------- RMSNorms for dt (256), B (16), C (16) --------------------
__global__ __launch_bounds__(64) void norms_kernel(
    const float* __restrict__ ssmp, const float* __restrict__ dtw,
    const float* __restrict__ bw, const float* __restrict__ cwn,
    ushort* __restrict__ dtn, float* __restrict__ Bn, float* __restrict__ Cn) {
  int l = blockIdx.x, lane = threadIdx.x;
  const float* row = ssmp + (size_t)l * NPAD;
  float4 v = ((const float4*)row)[lane];
  float va[4] = {v.x, v.y, v.z, v.w};
  float ss = va[0]*va[0] + va[1]*va[1] + va[2]*va[2] + va[3]*va[3];
#pragma unroll
  for (int m = 32; m >= 1; m >>= 1) ss += __shfl_xor(ss, m);
  float rs = rsqrtf(ss * (1.f / 256.f) + 1e-6f);
  float4 w = ((const float4*)dtw)[lane];
  float wa[4] = {w.x, w.y, w.z, w.w};
  union { ushort us[4]; uint2 v2; } o;
#pragma unroll
  for (int j = 0; j < 4; ++j) o.us[j] = f2b(va[j] * rs * wa[j]);
  ((uint2*)(dtn + (size_t)l * 256))[lane] = o.v2;

  int g = lane & 15;
  float bv = row[256 + g], cv = row[272 + g];
  float bs = bv * bv, cs = cv * cv;
#pragma unroll
  for (int m = 8; m >= 1; m >>= 1) {
    bs += __shfl_xor(bs, m);
    cs += __shfl_xor(cs, m);
  }
  if (lane < 16) {
    Bn[(size_t)l * NST + lane] = bv * rsqrtf(bs * (1.f / 16.f) + 1e-6f) * bw[lane];
    Cn[(size_t)l * NST + lane] = cv * rsqrtf(cs * (1.f / 16.f) + 1e-6f) * cwn[lane];
  }
}

// ---------------- selective scan, chunked over L ----------------------------
__global__ __launch_bounds__(256) void scan_phase1(
    const float* __restrict__ delta, const ushort* __restrict__ uc,
    const float* __restrict__ Bn, const float* __restrict__ Am,
    float* __restrict__ Sbuf, float* __restrict__ Pbuf) {
  __shared__ float sB[CLEN * NST];
  const int tid = threadIdx.x;
  const int d = blockIdx.x * 256 + tid;
  const int c = blockIdx.y, l0 = c * CLEN;
  {
    const float4* bsrc = (const float4*)(Bn + (size_t)l0 * NST);
    float4* bdst = (float4*)sB;
    for (int i = tid; i < CLEN * NST / 4; i += 256) bdst[i] = bsrc[i];
  }
  __syncthreads();
  float A[16];
#pragma unroll
  for (int j = 0; j < 4; ++j) {
    float4 a4 = ((const float4*)(Am + (size_t)d * NST))[j];
    A[4*j] = a4.x; A[4*j+1] = a4.y; A[4*j+2] = a4.z; A[4*j+3] = a4.w;
  }
  float st[16] = {};
  float sd = 0.f;
  const size_t base = (size_t)l0 * DDIM + d;
  float dx0 = delta[base],            dx1 = delta[base + DDIM];
  float ux0 = b2f(uc[base]),          ux1 = b2f(uc[base + DDIM]);
  for (int l = 0; l < CLEN; l += 2) {
    int lp = (l + 2 < CLEN) ? l + 2 : CLEN - 2;
    float dxn0 = delta[base + (size_t)lp * DDIM];
    float dxn1 = delta[base + (size_t)(lp + 1) * DDIM];
    float uxn0 = b2f(uc[base + (size_t)lp * DDIM]);
    float uxn1 = b2f(uc[base + (size_t)(lp + 1) * DDIM]);
    sd += dx0;
    float dxu = dx0 * ux0;
#pragma unroll
    for (int n = 0; n < 16; ++n)
      st[n] = fmaf(__expf(dx0 * A[n]), st[n], dxu * sB[l * NST + n]);
    sd += dx1;
    dxu = dx1 * ux1;
#pragma unroll
    for (int n = 0; n < 16; ++n)
      st[n] = fmaf(__expf(dx1 * A[n]), st[n], dxu * sB[(l + 1) * NST + n]);
    dx0 = dxn0; dx1 = dxn1; ux0 = uxn0; ux1 = uxn1;
  }
  float4* Sd = (float4*)(Sbuf + ((size_t)c * DDIM + d) * NST);
  float4* Pd = (float4*)(Pbuf + ((size_t)c * DDIM + d) * NST);
#pragma unroll
  for (int j = 0; j < 4; ++j) {
    Sd[j] = make_float4(st[4*j], st[4*j+1], st[4*j+2], st[4*j+3]);
    Pd[j] = make_float4(__expf(A[4*j] * sd),   __expf(A[4*j+1] * sd),
                        __expf(A[4*j+2] * sd), __expf(A[4*j+3] * sd));
  }
}

__global__ __launch_bounds__(256) void scan_phase2(
    const float* __restrict__ Sbuf, float* __restrict__ Pbuf) {
  size_t t = (size_t)blockIdx.x * 256 + threadIdx.x;
  const size_t stride = (size_t)DDIM * NST;
  float s = 0.f;
  for (int c = 0; c < NC; ++c) {
    float P = Pbuf[c * stride + t];
    float S = Sbuf[c * stride + t];
    Pbuf[c * stride + t] = s;
    s = fmaf(P, s, S);
  }
}

__global__ __launch_bounds__(256) void scan_phase3(
    const float* __restrict__ delta, const ushort* __restrict__ uc,
    const float* __restrict__ Bn, const float* __restrict__ Cn,
    const float* __restrict__ Am, const float* __restrict__ Ibuf,
    const float* __restrict__ gbuf, const float* __restrict__ Dp,
    ushort* __restrict__ yg) {
  __shared__ float sB[CLEN * NST];
  __shared__ float sC[CLEN * NST];
  const int tid = threadIdx.x;
  const int d = blockIdx.x * 256 + tid;
  const int c = blockIdx.y, l0 = c * CLEN;
  {
    const float4* bsrc = (const float4*)(Bn + (size_t)l0 * NST);
    const float4* csrc = (const float4*)(Cn + (size_t)l0 * NST);
    float4* bdst = (float4*)sB;
    float4* cdst = (float4*)sC;
    for (int i = tid; i < CLEN * NST / 4; i += 256) {
      bdst[i] = bsrc[i];
      cdst[i] = csrc[i];
    }
  }
  __syncthreads();
  float A[16], st[16];
#pragma unroll
  for (int j = 0; j < 4; ++j) {
    float4 a4 = ((const float4*)(Am + (size_t)d * NST))[j];
    A[4*j] = a4.x; A[4*j+1] = a4.y; A[4*j+2] = a4.z; A[4*j+3] = a4.w;
    float4 s4 = ((const float4*)(Ibuf + ((size_t)c * DDIM + d) * NST))[j];
    st[4*j] = s4.x; st[4*j+1] = s4.y; st[4*j+2] = s4.z; st[4*j+3] = s4.w;
  }
  const float Dpd = Dp[d];
  const size_t base = (size_t)l0 * DDIM + d;
  float dx0 = delta[base],   dx1 = delta[base + DDIM];
  float ux0 = b2f(uc[base]), ux1 = b2f(uc[base + DDIM]);
  float g0  = gbuf[base],    g1  = gbuf[base + DDIM];
  for (int l = 0; l < CLEN; l += 2) {
    int lp = (l + 2 < CLEN) ? l + 2 : CLEN - 2;
    float dxn0 = delta[base + (size_t)lp * DDIM];
    float dxn1 = delta[base + (size_t)(lp + 1) * DDIM];
    float uxn0 = b2f(uc[base + (size_t)lp * DDIM]);
    float uxn1 = b2f(uc[base + (size_t)(lp + 1) * DDIM]);
    float gn0  = gbuf[base + (size_t)lp * DDIM];
    float gn1  = gbuf[base + (size_t)(lp + 1) * DDIM];
    {
      float dxu = dx0 * ux0, y0 = 0.f, y1 = 0.f;
#pragma unroll
      for (int n = 0; n < 16; n += 2) {
        st[n]   = fmaf(__expf(dx0 * A[n]),   st[n],   dxu * sB[l * NST + n]);
        st[n+1] = fmaf(__expf(dx0 * A[n+1]), st[n+1], dxu * sB[l * NST + n+1]);
        y0 = fmaf(st[n],   sC[l * NST + n],   y0);
        y1 = fmaf(st[n+1], sC[l * NST + n+1], y1);
      }
      float o = (y0 + y1 + ux0 * Dpd) * (g0 / (1.f + __expf(-g0)));
      yg[base + (size_t)l * DDIM] = f2b(o);
    }
    {
      float dxu = dx1 * ux1, y0 = 0.f, y1 = 0.f;
#pragma unroll
      for (int n = 0; n < 16; n += 2) {
        st[n]   = fmaf(__expf(dx1 * A[n]),   st[n],   dxu * sB[(l+1) * NST + n]);
        st[n+1] = fmaf(__expf(dx1 * A[n+1]), st[n+1], dxu * sB[(l+1) * NST + n+1]);
        y0 = fmaf(st[n],   sC[(l+1) * NST + n],   y0);
        y1 = fmaf(st[n+1], sC[(l+1) * NST + n+1], y1);
      }
      float o = (y0 + y1 + ux1 * Dpd) * (g1 / (1.f + __expf(-g1)));
      yg[base + (size_t)(l + 1) * DDIM] = f2b(o);
    }
    dx0 = dxn0; dx1 = dxn1; ux0 = uxn0; ux1 = uxn1; g0 = gn0; g1 = gn1;
  }
}

// ---------------------------------------------------------------------------
extern "C" void kernel_launch(void* const* d_in, const int* in_sizes, int n_in,
                              void* d_out, int out_size, void* d_ws, size_t ws_size,
                              hipStream_t stream) {
  (void)in_sizes; (void)n_in; (void)out_size; (void)ws_size;
  const float* hs   = (const float*)d_in[0];
  const float* W_in = (const float*)d_in[1];
  const float* cw   = (const float*)d_in[2];
  const float* cb   = (const float*)d_in[3];
  const float* Wx   = (const float*)d_in[4];
  const float* dtw  = (const float*)d_in[5];
  const float* bw   = (const float*)d_in[6];
  const float* cwn  = (const float*)d_in[7];
  const float* Wdt  = (const float*)d_in[8];
  const float* dtb  = (const float*)d_in[9];
  const float* Am   = (const float*)d_in[10];
  const float* Dp   = (const float*)d_in[11];
  const float* Wout = (const float*)d_in[12];
  float* out = (float*)d_out;

  char* ws = (char*)d_ws;
  const size_t MB = 1ull << 20;
  // region A (128MB): win_b for in_proj; after: delta (64MB) + wout_b (64MB)
  ushort* win_b  = (ushort*)(ws);
  float*  delta  = (float*) (ws);
  ushort* wout_b = (ushort*)(ws + 64 * MB);
  // region B (64MB): ubuf for conv; then Cp(24)+Sbuf(8)+Pbuf(8); then Cp2(64)
  float*  ubuf   = (float*) (ws + 128 * MB);
  float*  Cp     = (float*) (ws + 128 * MB);
  float*  Cp2    = (float*) (ws + 128 * MB);
  float*  Sbuf   = (float*) (ws + 152 * MB);
  float*  Pbuf   = (float*) (ws + 160 * MB);
  float*  gbuf   = (float*) (ws + 192 * MB);          // 64MB
  ushort* hs_b   = (ushort*)(ws + 256 * MB);          // 16MB
  ushort* wxp_b  = (ushort*)(ws + 272 * MB);          // 6MB
  ushort* wdt_b  = (ushort*)(ws + 278 * MB);          // 4MB
  ushort* ucv    = (ushort*)(ws + 282 * MB);          // 32MB
  float*  ssmp   = (float*) (ws + 314 * MB);          // 3MB
  ushort* dtn    = (ushort*)(ws + 317 * MB);          // 1MB
  float*  Bn     = (float*) (ws + 318 * MB);
  float*  Cn     = (float*) (ws + 318 * MB + 131072);
  ushort* yg     = (ushort*)(ws + 319 * MB);          // 32MB; end 351MB

  // f32 -> bf16 conversions
  cvt_kernel<<<67108864 / 2048, 256, 0, stream>>>(W_in, win_b, 67108864 / 8);
  cvt_kernel<<<8388608 / 2048, 256, 0, stream>>>(hs, hs_b, 8388608 / 8);
  cvt_kernel<<<2359296 / 2048, 256, 0, stream>>>(Wx, wxp_b, 2359296 / 8);
  hipMemsetAsync((char*)wxp_b + 4718592, 0, 1572864, stream);
  cvt_kernel<<<2097152 / 2048, 256, 0, stream>>>(Wdt, wdt_b, 2097152 / 8);

  // 1) in_proj (8-phase 256^2): u and gate halves
  gemm8p<<<dim3(32, 8), 512, 0, stream>>>(hs_b, win_b, ubuf,
                                          2048, DDIM, 4096, 4096);
  gemm8p<<<dim3(32, 8), 512, 0, stream>>>(hs_b, win_b + (size_t)DDIM * 4096,
                                          gbuf, 2048, DDIM, 4096, 4096);
  cvt_kernel<<<33554432 / 2048, 256, 0, stream>>>(Wout, wout_b, 33554432 / 8);

  // 2) causal conv + SiLU -> u_conv bf16
  conv_silu_kernel<<<dim3(32, 2048), 256, 0, stream>>>(ubuf, cw, cb, ucv);

  // 3) x_proj, split-K x8 -> partials, reduce
  gemm_nt<0><<<dim3(3, 16, 8), 256, 0, stream>>>(ucv, wxp_b, Cp,
                                                 2048, NPAD, 8192, 1024, nullptr);
  reduce8_kernel<<<3072, 256, 0, stream>>>(Cp, ssmp);

  // 4) RMSNorms
  norms_kernel<<<2048, 64, 0, stream>>>(ssmp, dtw, bw, cwn, dtn, Bn, Cn);

  // 5) dt_proj + softplus
  gemm_nt<1><<<dim3(64, 16), 256, 0, stream>>>(dtn, wdt_b, delta,
                                               2048, DDIM, 256, 256, dtb);

  // 6) chunked selective scan; phase3 fuses skip+gate -> yg bf16
  scan_phase1<<<dim3(32, NC), 256, 0, stream>>>(delta, ucv, Bn, Am, Sbuf, Pbuf);
  scan_phase2<<<512, 256, 0, stream>>>(Sbuf, Pbuf);
  scan_phase3<<<dim3(32, NC), 256, 0, stream>>>(delta, ucv, Bn, Cn, Am, Pbuf,
                                                gbuf, Dp, yg);

  // 7) out_proj (8-phase, split-K x2) -> reduce into d_out
  gemm8p<<<dim3(16, 8, 2), 512, 0, stream>>>(yg, wout_b, Cp2,
                                             2048, HDIM, 8192, 4096);
  reduce2_kernel<<<(LSEQ * HDIM / 4) / 256, 256, 0, stream>>>(Cp2, out);
}

// Round 4
// 881.977 us; speedup vs baseline: 1.6213x; 1.0127x over previous
//
#include <hip/hip_runtime.h>
#include <stdint.h>

// ---------------------------------------------------------------------------
// JambaMambaMixer: B=1, L=2048, H=4096, D=8192, N=16, K=4, R=256
// R3: XCD-chunked block mapping for gemm8p (8m x 4n per XCD for in_proj,
//     4m x 4n x 2z for out_proj) to kill the 284MB B-panel L2-miss stream;
//     gate half stored bf16.
// ---------------------------------------------------------------------------

#define LSEQ 2048
#define HDIM 4096
#define DDIM 8192
#define NST  16
#define NPAD 384   // R + 2N = 288 padded to 3*128
#define NC   16    // scan chunks
#define CLEN 128   // LSEQ / NC

typedef __bf16 bf16x8 __attribute__((ext_vector_type(8)));
typedef float  f32x4  __attribute__((ext_vector_type(4)));

__device__ __forceinline__ ushort f2b(float f) {
  uint32_t x = __float_as_uint(f);
  x += 0x7FFFu + ((x >> 16) & 1u);           // RNE
  return (ushort)(x >> 16);
}
__device__ __forceinline__ float b2f(ushort u) {
  return __uint_as_float(((uint32_t)u) << 16);
}

__device__ __forceinline__ void gload_lds16(const ushort* g, ushort* l) {
  __builtin_amdgcn_global_load_lds(
      (const __attribute__((address_space(1))) void*)g,
      (__attribute__((address_space(3))) void*)l, 16, 0, 0);
}

// ---------------- f32 -> bf16 conversion (8 elems/thread) ------------------
__global__ __launch_bounds__(256) void cvt_kernel(const float* __restrict__ s,
                                                  ushort* __restrict__ d,
                                                  size_t n8) {
  size_t i = (size_t)blockIdx.x * 256 + threadIdx.x;
  if (i >= n8) return;
  const float4* sp = (const float4*)s;
  float4 a = sp[2 * i], b = sp[2 * i + 1];
  union { ushort us[8]; uint4 v; } u;
  u.us[0] = f2b(a.x); u.us[1] = f2b(a.y); u.us[2] = f2b(a.z); u.us[3] = f2b(a.w);
  u.us[4] = f2b(b.x); u.us[5] = f2b(b.y); u.us[6] = f2b(b.z); u.us[7] = f2b(b.w);
  ((uint4*)d)[i] = u.v;
}

// ======================= 8-phase 256x256 bf16 NT GEMM =======================
// C[M,N] = A[M,K] * Bw[N,K]^T. 512 thr = 8 waves (2m x 4n), per-wave 128x64.
// BK=64, double-buffered 128KiB LDS, per-phase stage, vmcnt(6) at phases 4/8.
// MODE 0: XCD chunk = 8m x (nbx/8)n, requires gridDim.y==8, gridDim.x%8==0.
// MODE 1: XCD chunk = 4m x 4n x 2z, requires grid (16,8,2).
// OUT 0: f32 store; OUT 1: bf16 store.
template <int MODE, int OUT>
__global__ __launch_bounds__(512, 2) void gemm8p(
    const ushort* __restrict__ A, const ushort* __restrict__ Bw,
    void* __restrict__ Cv, int M, int N, int ldk, int Kc) {
  __shared__ __align__(16) ushort As[2][256 * 64];
  __shared__ __align__(16) ushort Bs[2][256 * 64];
  const int tid  = threadIdx.x;
  const int lane = tid & 63;
  const int w    = tid >> 6;     // wave 0..7
  const int wr   = w >> 2;       // m half 0..1
  const int wc   = w & 3;        // n quarter 0..3

  // XCD-aware chunked block mapping (hardware round-robins bid -> XCD)
  const int glob = (blockIdx.z * gridDim.y + blockIdx.y) * gridDim.x + blockIdx.x;
  const int k8 = glob & 7, j = glob >> 3;
  int mt, nt, zz;
  if (MODE == 0) {
    mt = j & 7;                            // all 8 m-tiles per XCD
    nt = k8 * (gridDim.x >> 3) + (j >> 3); // npx n-tiles per XCD
    zz = 0;
  } else {
    mt = (k8 & 1) * 4 + (j & 3);           // 4 m-tiles
    nt = (k8 >> 1) * 4 + ((j >> 2) & 3);   // 4 n-tiles
    zz = j >> 4;                           // 2 K-slices
  }
  const int m0 = mt * 256, n0 = nt * 256;
  const int kbeg = zz * Kc;
  float*  C  = (float*) Cv + (size_t)zz * M * N;
  ushort* Cb = (ushort*)Cv + (size_t)zz * M * N;
  const int NT = Kc >> 6;        // even, >= 2

  // staging constants: 16B slot pre-swizzle (involution)
  const int srck = (lane & 7) ^ ((lane >> 3) & 7);
  const int astripe = w >> 2, awl = w & 3;
  const int arow_st = astripe * 128 + awl * 8 + (lane >> 3);
  const ushort* Abase = A + (size_t)(m0 + arow_st) * ldk + kbeg + srck * 8;
  const int aldsb = (astripe * 128 + awl * 8) * 64;
  const int brow_st = w * 8 + (lane >> 3);
  const ushort* Bbase = Bw + (size_t)(n0 + brow_st) * ldk + kbeg + srck * 8;
  const int bldsb = (w * 8) * 64;

  // read-side constants
  const int lrow = lane & 15;
  const int kch  = lane >> 4;
  const int axor = lrow & 7;

  auto stA = [&](int buf, int kt, int q) {
    gload_lds16(Abase + (size_t)q * 32 * ldk + kt * 64,
                &As[buf][aldsb + q * 32 * 64]);
  };
  auto stB = [&](int buf, int kt, int half, int jj) {
    gload_lds16(Bbase + (size_t)(half * 128 + jj * 64) * ldk + kt * 64,
                &Bs[buf][bldsb + (half * 128 + jj * 64) * 64]);
  };
  auto rdA = [&](int buf, int mi, int sl) -> bf16x8 {
    int arow = wr * 128 + mi * 16 + lrow;
    int s4 = sl * 4 + kch;
    return *(const bf16x8*)&As[buf][arow * 64 + ((s4 ^ axor) << 3)];
  };
  auto rdB = [&](int buf, int ni, int sl) -> bf16x8 {
    int brow = wc * 64 + ni * 16 + lrow;
    int s4 = sl * 4 + kch;
    return *(const bf16x8*)&Bs[buf][brow * 64 + ((s4 ^ axor) << 3)];
  };

  f32x4 acc[8][4] = {};

  // prologue: t0 full (B h0,h1 + A q0..q3), t1 partial (B h0,h1 + A q0,q1)
  stB(0, 0, 0, 0); stB(0, 0, 0, 1); stB(0, 0, 1, 0); stB(0, 0, 1, 1);
  stA(0, 0, 0); stA(0, 0, 1); stA(0, 0, 2); stA(0, 0, 3);
  stB(1, 1, 0, 0); stB(1, 1, 0, 1); stB(1, 1, 1, 0); stB(1, 1, 1, 1);
  stA(1, 1, 0); stA(1, 1, 1);
  asm volatile("s_waitcnt vmcnt(6)" ::: "memory");   // t0 fully landed
  asm volatile("s_barrier" ::: "memory");

#define PHASE(BUF, Q, STAGES)                                                 \
  {                                                                           \
    if (Q == 0) {                                                             \
      _Pragma("unroll") for (int ni = 0; ni < 4; ++ni)                        \
        _Pragma("unroll") for (int sl = 0; sl < 2; ++sl)                      \
          bfr[ni][sl] = rdB(BUF, ni, sl);                                     \
    }                                                                         \
    _Pragma("unroll") for (int m2 = 0; m2 < 2; ++m2)                          \
      _Pragma("unroll") for (int sl = 0; sl < 2; ++sl)                        \
        afr[m2][sl] = rdA(BUF, Q * 2 + m2, sl);                               \
    STAGES;                                                                   \
    asm volatile("s_barrier" ::: "memory");                                   \
    __builtin_amdgcn_s_setprio(1);                                            \
    _Pragma("unroll") for (int sl = 0; sl < 2; ++sl)                          \
      _Pragma("unroll") for (int m2 = 0; m2 < 2; ++m2)                        \
        _Pragma("unroll") for (int ni = 0; ni < 4; ++ni)                      \
          acc[Q * 2 + m2][ni] = __builtin_amdgcn_mfma_f32_16x16x32_bf16(      \
              afr[m2][sl], bfr[ni][sl], acc[Q * 2 + m2][ni], 0, 0, 0);        \
    __builtin_amdgcn_s_setprio(0);                                            \
  }

  for (int t = 0; t < NT; t += 2) {
    const int t2 = (t + 2 < NT) ? t + 2 : 0;   // wrap-guard: valid mem, unread
    const int t3 = (t + 3 < NT) ? t + 3 : 0;
    bf16x8 bfr[4][2], afr[2][2];
    // group 0: tile t in buf0
    PHASE(0, 0, { stA(1, t + 1, 2); stA(1, t + 1, 3); });
    asm volatile("s_barrier" ::: "memory");
    PHASE(0, 1, { stB(0, t2, 0, 0); stB(0, t2, 0, 1); });
    asm volatile("s_barrier" ::: "memory");
    PHASE(0, 2, { stB(0, t2, 1, 0); stB(0, t2, 1, 1); });
    asm volatile("s_barrier" ::: "memory");
    PHASE(0, 3, { stA(0, t2, 0); stA(0, t2, 1); });
    asm volatile("s_waitcnt vmcnt(6)" ::: "memory");
    asm volatile("s_barrier" ::: "memory");
    // group 1: tile t+1 in buf1
    PHASE(1, 0, { stA(0, t2, 2); stA(0, t2, 3); });
    asm volatile("s_barrier" ::: "memory");
    PHASE(1, 1, { stB(1, t3, 0, 0); stB(1, t3, 0, 1); });
    asm volatile("s_barrier" ::: "memory");
    PHASE(1, 2, { stB(1, t3, 1, 0); stB(1, t3, 1, 1); });
    asm volatile("s_barrier" ::: "memory");
    PHASE(1, 3, { stA(1, t3, 0); stA(1, t3, 1); });
    asm volatile("s_waitcnt vmcnt(6)" ::: "memory");
    asm volatile("s_barrier" ::: "memory");
  }
#undef PHASE

  asm volatile("s_waitcnt vmcnt(0)" ::: "memory");   // drain tail stages
  // epilogue: C/D layout col=lane&15, row=(lane>>4)*4+q
#pragma unroll
  for (int mi = 0; mi < 8; ++mi) {
    int row0 = m0 + wr * 128 + mi * 16 + kch * 4;
#pragma unroll
    for (int ni = 0; ni < 4; ++ni) {
      int col = n0 + wc * 64 + ni * 16 + lrow;
#pragma unroll
      for (int q_ = 0; q_ < 4; ++q_) {
        if (OUT == 0)
          C[(size_t)(row0 + q_) * N + col] = acc[mi][ni][q_];
        else
          Cb[(size_t)(row0 + q_) * N + col] = f2b(acc[mi][ni][q_]);
      }
    }
  }
}

// ---------------- 128x128 bf16 NT GEMM (narrow shapes) ----------------------
template <int EPI>
__global__ __launch_bounds__(256) void gemm_nt(
    const ushort* __restrict__ A, const ushort* __restrict__ Bw,
    float* __restrict__ C, int M, int N, int ldk, int Kc,
    const float* __restrict__ bias) {
  __shared__ __align__(16) ushort As[128 * 64];
  __shared__ __align__(16) ushort Bs[128 * 64];
  const int tid  = threadIdx.x;
  const int lane = tid & 63;
  const int wid  = tid >> 6;
  const int wr = wid >> 1, wc = wid & 1;
  const int m0 = blockIdx.y * 128, n0 = blockIdx.x * 128;
  const int kbeg = blockIdx.z * Kc;
  C += (size_t)blockIdx.z * M * N;
  const int rr0 = tid >> 3;
  const int sl  = tid & 7;
  const int lrow = lane & 15;
  const int lks  = lane >> 4;

  f32x4 acc[4][4] = {};

  for (int k0 = kbeg; k0 < kbeg + Kc; k0 += 64) {
#pragma unroll
    for (int i = 0; i < 4; ++i) {
      int rr  = i * 32 + rr0;
      int ksl = sl ^ (rr & 7);
      const ushort* ga = A  + (size_t)(m0 + rr) * ldk + k0 + ksl * 8;
      const ushort* gb = Bw + (size_t)(n0 + rr) * ldk + k0 + ksl * 8;
      ushort* la = As + (i * 256 + (wid << 6)) * 8;
      ushort* lb = Bs + (i * 256 + (wid << 6)) * 8;
      gload_lds16(ga, la);
      gload_lds16(gb, lb);
    }
    __syncthreads();
#pragma unroll
    for (int kc = 0; kc < 2; ++kc) {
      bf16x8 av[4], bv[4];
#pragma unroll
      for (int mi = 0; mi < 4; ++mi) {
        int row = wr * 64 + mi * 16 + lrow;
        int ks  = kc * 4 + lks;
        av[mi] = *(const bf16x8*)(As + row * 64 + ((ks ^ (row & 7)) << 3));
      }
#pragma unroll
      for (int ni = 0; ni < 4; ++ni) {
        int row = wc * 64 + ni * 16 + lrow;
        int ks  = kc * 4 + lks;
        bv[ni] = *(const bf16x8*)(Bs + row * 64 + ((ks ^ (row & 7)) << 3));
      }
#pragma unroll
      for (int mi = 0; mi < 4; ++mi)
#pragma unroll
        for (int ni = 0; ni < 4; ++ni)
          acc[mi][ni] = __builtin_amdgcn_mfma_f32_16x16x32_bf16(
              av[mi], bv[ni], acc[mi][ni], 0, 0, 0);
    }
    __syncthreads();
  }

#pragma unroll
  for (int mi = 0; mi < 4; ++mi) {
    int row0 = m0 + wr * 64 + mi * 16 + (lks << 2);
#pragma unroll
    for (int ni = 0; ni < 4; ++ni) {
      int col = n0 + wc * 64 + ni * 16 + lrow;
      float bcol = 0.f;
      if (EPI == 1) bcol = bias[col];
#pragma unroll
      for (int q = 0; q < 4; ++q) {
        float v = acc[mi][ni][q];
        if (EPI == 1) {
          v += bcol;
          v = (v > 20.f) ? v : log1pf(__expf(v));
        }
        C[(size_t)(row0 + q) * N + col] = v;
      }
    }
  }
}

// ---------------- split-K reduces -------------------------------------------
__global__ __launch_bounds__(256) void reduce8_kernel(
    const float* __restrict__ Cp, float* __restrict__ out) {
  size_t i = (size_t)blockIdx.x * 256 + threadIdx.x;
  const size_t MN = (size_t)LSEQ * NPAD;
  float s = 0.f;
#pragma unroll
  for (int z = 0; z < 8; ++z) s += Cp[z * MN + i];
  out[i] = s;
}

__global__ __launch_bounds__(256) void reduce2_kernel(
    const float* __restrict__ Cp, float* __restrict__ out) {
  size_t i = (size_t)blockIdx.x * 256 + threadIdx.x;
  const size_t MN4 = (size_t)LSEQ * HDIM / 4;
  float4 a = ((const float4*)Cp)[i];
  float4 b = ((const float4*)Cp)[MN4 + i];
  ((float4*)out)[i] = make_float4(a.x + b.x, a.y + b.y, a.z + b.z, a.w + b.w);
}

// ---------------- causal depthwise conv1d (K=4) + bias + SiLU --------------
__global__ __launch_bounds__(256) void conv_silu_kernel(
    const float* __restrict__ ubuf, const float* __restrict__ cw,
    const float* __restrict__ cb, ushort* __restrict__ uc) {
  int d = blockIdx.x * 256 + threadIdx.x;
  int l = blockIdx.y;
  float4 w4 = ((const float4*)cw)[d];
  float wa[4] = {w4.x, w4.y, w4.z, w4.w};
  float s = cb[d];
#pragma unroll
  for (int j = 0; j < 4; ++j) {
    int li = l - 3 + j;
    if (li >= 0) s += wa[j] * ubuf[(size_t)li * DDIM + d];
  }
  float o = s / (1.f + __expf(-s));
  uc[(size_t)l * DDIM + d] = f2b(o);
}

// ---------------- RMSNorms for dt (256), B (16), C (16) --------------------
__global__ __launch_bounds__(64) void norms_kernel(
    const float* __restrict__ ssmp, const float* __restrict__ dtw,
    const float* __restrict__ bw, const float* __restrict__ cwn,
    ushort* __restrict__ dtn, float* __restrict__ Bn, float* __restrict__ Cn) {
  int l = blockIdx.x, lane = threadIdx.x;
  const float* row = ssmp + (size_t)l * NPAD;
  float4 v = ((const float4*)row)[lane];
  float va[4] = {v.x, v.y, v.z, v.w};
  float ss = va[0]*va[0] + va[1]*va[1] + va[2]*va[2] + va[3]*va[3];
#pragma unroll
  for (int m = 32; m >= 1; m >>= 1) ss += __shfl_xor(ss, m);
  float rs = rsqrtf(ss * (1.f / 256.f) + 1e-6f);
  float4 w = ((const float4*)dtw)[lane];
  float wa[4] = {w.x, w.y, w.z, w.w};
  union { ushort us[4]; uint2 v2; } o;
#pragma unroll
  for (int j = 0; j < 4; ++j) o.us[j] = f2b(va[j] * rs * wa[j]);
  ((uint2*)(dtn + (size_t)l * 256))[lane] = o.v2;

  int g = lane & 15;
  float bv = row[256 + g], cv = row[272 + g];
  float bs = bv * bv, cs = cv * cv;
#pragma unroll
  for (int m = 8; m >= 1; m >>= 1) {
    bs += __shfl_xor(bs, m);
    cs += __shfl_xor(cs, m);
  }
  if (lane < 16) {
    Bn[(size_t)l * NST + lane] = bv * rsqrtf(bs * (1.f / 16.f) + 1e-6f) * bw[lane];
    Cn[(size_t)l * NST + lane] = cv * rsqrtf(cs * (1.f / 16.f) + 1e-6f) * cwn[lane];
  }
}

// ---------------- selective scan, chunked over L ----------------------------
__global__ __launch_bounds__(256) void scan_phase1(
    const float* __restrict__ delta, const ushort* __restrict__ uc,
    const float* __restrict__ Bn, const float* __restrict__ Am,
    float* __restrict__ Sbuf, float* __restrict__ Pbuf) {
  __shared__ float sB[CLEN * NST];
  const int tid = threadIdx.x;
  const int d = blockIdx.x * 256 + tid;
  const int c = blockIdx.y, l0 = c * CLEN;
  {
    const float4* bsrc = (const float4*)(Bn + (size_t)l0 * NST);
    float4* bdst = (float4*)sB;
    for (int i = tid; i < CLEN * NST / 4; i += 256) bdst[i] = bsrc[i];
  }
  __syncthreads();
  float A[16];
#pragma unroll
  for (int j = 0; j < 4; ++j) {
    float4 a4 = ((const float4*)(Am + (size_t)d * NST))[j];
    A[4*j] = a4.x; A[4*j+1] = a4.y; A[4*j+2] = a4.z; A[4*j+3] = a4.w;
  }
  float st[16] = {};
  float sd = 0.f;
  const size_t base = (size_t)l0 * DDIM + d;
  float dx0 = delta[base],            dx1 = delta[base + DDIM];
  float ux0 = b2f(uc[base]),          ux1 = b2f(uc[base + DDIM]);
  for (int l = 0; l < CLEN; l += 2) {
    int lp = (l + 2 < CLEN) ? l + 2 : CLEN - 2;
    float dxn0 = delta[base + (size_t)lp * DDIM];
    float dxn1 = delta[base + (size_t)(lp + 1) * DDIM];
    float uxn0 = b2f(uc[base + (size_t)lp * DDIM]);
    float uxn1 = b2f(uc[base + (size_t)(lp + 1) * DDIM]);
    sd += dx0;
    float dxu = dx0 * ux0;
#pragma unroll
    for (int n = 0; n < 16; ++n)
      st[n] = fmaf(__expf(dx0 * A[n]), st[n], dxu * sB[l * NST + n]);
    sd += dx1;
    dxu = dx1 * ux1;
#pragma unroll
    for (int n = 0; n < 16; ++n)
      st[n] = fmaf(__expf(dx1 * A[n]), st[n], dxu * sB[(l + 1) * NST + n]);
    dx0 = dxn0; dx1 = dxn1; ux0 = uxn0; ux1 = uxn1;
  }
  float4* Sd = (float4*)(Sbuf + ((size_t)c * DDIM + d) * NST);
  float4* Pd = (float4*)(Pbuf + ((size_t)c * DDIM + d) * NST);
#pragma unroll
  for (int j = 0; j < 4; ++j) {
    Sd[j] = make_float4(st[4*j], st[4*j+1], st[4*j+2], st[4*j+3]);
    Pd[j] = make_float4(__expf(A[4*j] * sd),   __expf(A[4*j+1] * sd),
                        __expf(A[4*j+2] * sd), __expf(A[4*j+3] * sd));
  }
}

__global__ __launch_bounds__(256) void scan_phase2(
    const float* __restrict__ Sbuf, float* __restrict__ Pbuf) {
  size_t t = (size_t)blockIdx.x * 256 + threadIdx.x;
  const size_t stride = (size_t)DDIM * NST;
  float s = 0.f;
  for (int c = 0; c < NC; ++c) {
    float P = Pbuf[c * stride + t];
    float S = Sbuf[c * stride + t];
    Pbuf[c * stride + t] = s;
    s = fmaf(P, s, S);
  }
}

__global__ __launch_bounds__(256) void scan_phase3(
    const float* __restrict__ delta, const ushort* __restrict__ uc,
    const float* __restrict__ Bn, const float* __restrict__ Cn,
    const float* __restrict__ Am, const float* __restrict__ Ibuf,
    const ushort* __restrict__ gbuf, const float* __restrict__ Dp,
    ushort* __restrict__ yg) {
  __shared__ float sB[CLEN * NST];
  __shared__ float sC[CLEN * NST];
  const int tid = threadIdx.x;
  const int d = blockIdx.x * 256 + tid;
  const int c = blockIdx.y, l0 = c * CLEN;
  {
    const float4* bsrc = (const float4*)(Bn + (size_t)l0 * NST);
    const float4* csrc = (const float4*)(Cn + (size_t)l0 * NST);
    float4* bdst = (float4*)sB;
    float4* cdst = (float4*)sC;
    for (int i = tid; i < CLEN * NST / 4; i += 256) {
      bdst[i] = bsrc[i];
      cdst[i] = csrc[i];
    }
  }
  __syncthreads();
  float A[16], st[16];
#pragma unroll
  for (int j = 0; j < 4; ++j) {
    float4 a4 = ((const float4*)(Am + (size_t)d * NST))[j];
    A[4*j] = a4.x; A[4*j+1] = a4.y; A[4*j+2] = a4.z; A[4*j+3] = a4.w;
    float4 s4 = ((const float4*)(Ibuf + ((size_t)c * DDIM + d) * NST))[j];
    st[4*j] = s4.x; st[4*j+1] = s4.y; st[4*j+2] = s4.z; st[4*j+3] = s4.w;
  }
  const float Dpd = Dp[d];
  const size_t base = (size_t)l0 * DDIM + d;
  float dx0 = delta[base],   dx1 = delta[base + DDIM];
  float ux0 = b2f(uc[base]), ux1 = b2f(uc[base + DDIM]);
  float g0  = b2f(gbuf[base]), g1 = b2f(gbuf[base + DDIM]);
  for (int l = 0; l < CLEN; l += 2) {
    int lp = (l + 2 < CLEN) ? l + 2 : CLEN - 2;
    float dxn0 = delta[base + (size_t)lp * DDIM];
    float dxn1 = delta[base + (size_t)(lp + 1) * DDIM];
    float uxn0 = b2f(uc[base + (size_t)lp * DDIM]);
    float uxn1 = b2f(uc[base + (size_t)(lp + 1) * DDIM]);
    float gn0  = b2f(gbuf[base + (size_t)lp * DDIM]);
    float gn1  = b2f(gbuf[base + (size_t)(lp + 1) * DDIM]);
    {
      float dxu = dx0 * ux0, y0 = 0.f, y1 = 0.f;
#pragma unroll
      for (int n = 0; n < 16; n += 2) {
        st[n]   = fmaf(__expf(dx0 * A[n]),   st[n],   dxu * sB[l * NST + n]);
        st[n+1] = fmaf(__expf(dx0 * A[n+1]), st[n+1], dxu * sB[l * NST + n+1]);
        y0 = fmaf(st[n],   sC[l * NST + n],   y0);
        y1 = fmaf(st[n+1], sC[l * NST + n+1], y1);
      }
      float o = (y0 + y1 + ux0 * Dpd) * (g0 / (1.f + __expf(-g0)));
      yg[base + (size_t)l * DDIM] = f2b(o);
    }
    {
      float dxu = dx1 * ux1, y0 = 0.f, y1 = 0.f;
#pragma unroll
      for (int n = 0; n < 16; n += 2) {
        st[n]   = fmaf(__expf(dx1 * A[n]),   st[n],   dxu * sB[(l+1) * NST + n]);
        st[n+1] = fmaf(__expf(dx1 * A[n+1]), st[n+1], dxu * sB[(l+1) * NST + n+1]);
        y0 = fmaf(st[n],   sC[(l+1) * NST + n],   y0);
        y1 = fmaf(st[n+1], sC[(l+1) * NST + n+1], y1);
      }
      float o = (y0 + y1 + ux1 * Dpd) * (g1 / (1.f + __expf(-g1)));
      yg[base + (size_t)(l + 1) * DDIM] = f2b(o);
    }
    dx0 = dxn0; dx1 = dxn1; ux0 = uxn0; ux1 = uxn1; g0 = gn0; g1 = gn1;
  }
}

// ---------------------------------------------------------------------------
extern "C" void kernel_launch(void* const* d_in, const int* in_sizes, int n_in,
                              void* d_out, int out_size, void* d_ws, size_t ws_size,
                              hipStream_t stream) {
  (void)in_sizes; (void)n_in; (void)out_size; (void)ws_size;
  const float* hs   = (const float*)d_in[0];
  const float* W_in = (const float*)d_in[1];
  const float* cw   = (const float*)d_in[2];
  const float* cb   = (const float*)d_in[3];
  const float* Wx   = (const float*)d_in[4];
  const float* dtw  = (const float*)d_in[5];
  const float* bw   = (const float*)d_in[6];
  const float* cwn  = (const float*)d_in[7];
  const float* Wdt  = (const float*)d_in[8];
  const float* dtb  = (const float*)d_in[9];
  const float* Am   = (const float*)d_in[10];
  const float* Dp   = (const float*)d_in[11];
  const float* Wout = (const float*)d_in[12];
  float* out = (float*)d_out;

  char* ws = (char*)d_ws;
  const size_t MB = 1ull << 20;
  // region A (128MB): win_b for in_proj; after: delta (64MB) + wout_b (64MB)
  ushort* win_b  = (ushort*)(ws);
  float*  delta  = (float*) (ws);
  ushort* wout_b = (ushort*)(ws + 64 * MB);
  // region B (64MB): ubuf for conv; then Cp(24)+Sbuf(8)+Pbuf(8); then Cp2(64)
  float*  ubuf   = (float*) (ws + 128 * MB);
  float*  Cp     = (float*) (ws + 128 * MB);
  float*  Cp2    = (float*) (ws + 128 * MB);
  float*  Sbuf   = (float*) (ws + 152 * MB);
  float*  Pbuf   = (float*) (ws + 160 * MB);
  ushort* gbuf   = (ushort*)(ws + 192 * MB);          // 32MB (bf16 gate)
  ushort* hs_b   = (ushort*)(ws + 256 * MB);          // 16MB
  ushort* wxp_b  = (ushort*)(ws + 272 * MB);          // 6MB
  ushort* wdt_b  = (ushort*)(ws + 278 * MB);          // 4MB
  ushort* ucv    = (ushort*)(ws + 282 * MB);          // 32MB
  float*  ssmp   = (float*) (ws + 314 * MB);          // 3MB
  ushort* dtn    = (ushort*)(ws + 317 * MB);          // 1MB
  float*  Bn     = (float*) (ws + 318 * MB);
  float*  Cn     = (float*) (ws + 318 * MB + 131072);
  ushort* yg     = (ushort*)(ws + 319 * MB);          // 32MB; end 351MB

  // f32 -> bf16 conversions
  cvt_kernel<<<67108864 / 2048, 256, 0, stream>>>(W_in, win_b, 67108864 / 8);
  cvt_kernel<<<8388608 / 2048, 256, 0, stream>>>(hs, hs_b, 8388608 / 8);
  cvt_kernel<<<2359296 / 2048, 256, 0, stream>>>(Wx, wxp_b, 2359296 / 8);
  hipMemsetAsync((char*)wxp_b + 4718592, 0, 1572864, stream);
  cvt_kernel<<<2097152 / 2048, 256, 0, stream>>>(Wdt, wdt_b, 2097152 / 8);

  // 1) in_proj (8-phase 256^2, XCD n-chunked): u (f32) and gate (bf16) halves
  gemm8p<0, 0><<<dim3(32, 8), 512, 0, stream>>>(hs_b, win_b, ubuf,
                                                2048, DDIM, 4096, 4096);
  gemm8p<0, 1><<<dim3(32, 8), 512, 0, stream>>>(hs_b, win_b + (size_t)DDIM * 4096,
                                                gbuf, 2048, DDIM, 4096, 4096);
  cvt_kernel<<<33554432 / 2048, 256, 0, stream>>>(Wout, wout_b, 33554432 / 8);

  // 2) causal conv + SiLU -> u_conv bf16
  conv_silu_kernel<<<dim3(32, 2048), 256, 0, stream>>>(ubuf, cw, cb, ucv);

  // 3) x_proj, split-K x8 -> partials, reduce
  gemm_nt<0><<<dim3(3, 16, 8), 256, 0, stream>>>(ucv, wxp_b, Cp,
                                                 2048, NPAD, 8192, 1024, nullptr);
  reduce8_kernel<<<3072, 256, 0, stream>>>(Cp, ssmp);

  // 4) RMSNorms
  norms_kernel<<<2048, 64, 0, stream>>>(ssmp, dtw, bw, cwn, dtn, Bn, Cn);

  // 5) dt_proj + softplus
  gemm_nt<1><<<dim3(64, 16), 256, 0, stream>>>(dtn, wdt_b, delta,
                                               2048, DDIM, 256, 256, dtb);

  // 6) chunked selective scan; phase3 fuses skip+gate -> yg bf16
  scan_phase1<<<dim3(32, NC), 256, 0, stream>>>(delta, ucv, Bn, Am, Sbuf, Pbuf);
  scan_phase2<<<512, 256, 0, stream>>>(Sbuf, Pbuf);
  scan_phase3<<<dim3(32, NC), 256, 0, stream>>>(delta, ucv, Bn, Cn, Am, Pbuf,
                                                gbuf, Dp, yg);

  // 7) out_proj (8-phase, 4m4n2z XCD chunks, split-K x2) -> reduce into d_out
  gemm8p<1, 0><<<dim3(16, 8, 2), 512, 0, stream>>>(yg, wout_b, Cp2,
                                                   2048, HDIM, 8192, 4096);
  reduce2_kernel<<<(LSEQ * HDIM / 4) / 256, 256, 0, stream>>>(Cp2, out);
}

// Round 5
// 813.316 us; speedup vs baseline: 1.7582x; 1.0844x over previous
//
#include <hip/hip_runtime.h>
#include <stdint.h>

// ---------------------------------------------------------------------------
// JambaMambaMixer: B=1, L=2048, H=4096, D=8192, N=16, K=4, R=256
// R4: gemm8p software-pipelined reads (fragments fetched one window ahead,
//     afr/bfr double-buffered) + single barrier per window (8/2-tiles, was 16).
//     bf16 u-half & delta, sliding-window conv, norms+reduce8 fused.
// ---------------------------------------------------------------------------

#define LSEQ 2048
#define HDIM 4096
#define DDIM 8192
#define NST  16
#define NPAD 384   // R + 2N = 288 padded to 3*128
#define NC   16    // scan chunks
#define CLEN 128   // LSEQ / NC

typedef __bf16 bf16x8 __attribute__((ext_vector_type(8)));
typedef float  f32x4  __attribute__((ext_vector_type(4)));

__device__ __forceinline__ ushort f2b(float f) {
  uint32_t x = __float_as_uint(f);
  x += 0x7FFFu + ((x >> 16) & 1u);           // RNE
  return (ushort)(x >> 16);
}
__device__ __forceinline__ float b2f(ushort u) {
  return __uint_as_float(((uint32_t)u) << 16);
}

__device__ __forceinline__ void gload_lds16(const ushort* g, ushort* l) {
  __builtin_amdgcn_global_load_lds(
      (const __attribute__((address_space(1))) void*)g,
      (__attribute__((address_space(3))) void*)l, 16, 0, 0);
}

// ---------------- f32 -> bf16 conversion (8 elems/thread) ------------------
__global__ __launch_bounds__(256) void cvt_kernel(const float* __restrict__ s,
                                                  ushort* __restrict__ d,
                                                  size_t n8) {
  size_t i = (size_t)blockIdx.x * 256 + threadIdx.x;
  if (i >= n8) return;
  const float4* sp = (const float4*)s;
  float4 a = sp[2 * i], b = sp[2 * i + 1];
  union { ushort us[8]; uint4 v; } u;
  u.us[0] = f2b(a.x); u.us[1] = f2b(a.y); u.us[2] = f2b(a.z); u.us[3] = f2b(a.w);
  u.us[4] = f2b(b.x); u.us[5] = f2b(b.y); u.us[6] = f2b(b.z); u.us[7] = f2b(b.w);
  ((uint4*)d)[i] = u.v;
}

// ======================= 8-phase 256x256 bf16 NT GEMM =======================
// C[M,N] = A[M,K]*Bw[N,K]^T. 512 thr = 8 waves (2m x 4n), per-wave 128x64.
// Reads pipelined ONE window ahead (afr/bfr double-buffered) -> MFMA starts
// with operands in regs; single s_barrier per window; vmcnt(6) at w3/w7 head.
// MODE 0: XCD chunk = 8m x (nbx/8)n (grid y==8, x%8==0).
// MODE 1: XCD chunk = 4m x 4n x 2z (grid (16,8,2)).
// OUT 0: f32 store; OUT 1: bf16 store.
template <int MODE, int OUT>
__global__ __launch_bounds__(512, 2) void gemm8p(
    const ushort* __restrict__ A, const ushort* __restrict__ Bw,
    void* __restrict__ Cv, int M, int N, int ldk, int Kc) {
  __shared__ __align__(16) ushort As[2][256 * 64];
  __shared__ __align__(16) ushort Bs[2][256 * 64];
  const int tid  = threadIdx.x;
  const int lane = tid & 63;
  const int w    = tid >> 6;     // wave 0..7
  const int wr   = w >> 2;       // m half 0..1
  const int wc   = w & 3;        // n quarter 0..3

  const int glob = (blockIdx.z * gridDim.y + blockIdx.y) * gridDim.x + blockIdx.x;
  const int k8 = glob & 7, j = glob >> 3;
  int mt, nt, zz;
  if (MODE == 0) {
    mt = j & 7;
    nt = k8 * (gridDim.x >> 3) + (j >> 3);
    zz = 0;
  } else {
    mt = (k8 & 1) * 4 + (j & 3);
    nt = (k8 >> 1) * 4 + ((j >> 2) & 3);
    zz = j >> 4;
  }
  const int m0 = mt * 256, n0 = nt * 256;
  const int kbeg = zz * Kc;
  const int NT = Kc >> 6;        // even, >= 4

  // staging constants: 16B slot pre-swizzle (involution)
  const int srck = (lane & 7) ^ ((lane >> 3) & 7);
  const int astripe = w >> 2, awl = w & 3;
  const int arow_st = astripe * 128 + awl * 8 + (lane >> 3);
  const ushort* Abase = A + (size_t)(m0 + arow_st) * ldk + kbeg + srck * 8;
  const int aldsb = (astripe * 128 + awl * 8) * 64;
  const int brow_st = w * 8 + (lane >> 3);
  const ushort* Bbase = Bw + (size_t)(n0 + brow_st) * ldk + kbeg + srck * 8;
  const int bldsb = (w * 8) * 64;

  // read-side constants
  const int lrow = lane & 15;
  const int kch  = lane >> 4;
  const int axor = lrow & 7;

  auto stA = [&](int buf, int kt, int q) {
    gload_lds16(Abase + (size_t)q * 32 * ldk + kt * 64,
                &As[buf][aldsb + q * 32 * 64]);
  };
  auto stB = [&](int buf, int kt, int half, int jj) {
    gload_lds16(Bbase + (size_t)(half * 128 + jj * 64) * ldk + kt * 64,
                &Bs[buf][bldsb + (half * 128 + jj * 64) * 64]);
  };
  auto rdA = [&](int buf, int mi, int sl) -> bf16x8 {
    int arow = wr * 128 + mi * 16 + lrow;
    int s4 = sl * 4 + kch;
    return *(const bf16x8*)&As[buf][arow * 64 + ((s4 ^ axor) << 3)];
  };
  auto rdB = [&](int buf, int ni, int sl) -> bf16x8 {
    int brow = wc * 64 + ni * 16 + lrow;
    int s4 = sl * 4 + kch;
    return *(const bf16x8*)&Bs[buf][brow * 64 + ((s4 ^ axor) << 3)];
  };

  f32x4 acc[8][4] = {};
  bf16x8 afr[2][2][2];   // [parity][m2][sl]
  bf16x8 bfr[2][4][2];   // [parity][ni][sl]

#define RDAQ(BUF, Q, AP)                                                      \
  { _Pragma("unroll") for (int m2 = 0; m2 < 2; ++m2)                          \
      _Pragma("unroll") for (int sl = 0; sl < 2; ++sl)                        \
        afr[AP][m2][sl] = rdA(BUF, (Q) * 2 + m2, sl); }
#define RDBALL(BUF, BP)                                                       \
  { _Pragma("unroll") for (int ni = 0; ni < 4; ++ni)                          \
      _Pragma("unroll") for (int sl = 0; sl < 2; ++sl)                        \
        bfr[BP][ni][sl] = rdB(BUF, ni, sl); }
#define MFMA16(MQ, AP, BP)                                                    \
  { asm volatile("s_barrier" ::: "memory");                                   \
    __builtin_amdgcn_s_setprio(1);                                            \
    _Pragma("unroll") for (int sl = 0; sl < 2; ++sl)                          \
      _Pragma("unroll") for (int m2 = 0; m2 < 2; ++m2)                        \
        _Pragma("unroll") for (int ni = 0; ni < 4; ++ni)                      \
          acc[(MQ) * 2 + m2][ni] = __builtin_amdgcn_mfma_f32_16x16x32_bf16(   \
              afr[AP][m2][sl], bfr[BP][ni][sl], acc[(MQ) * 2 + m2][ni],       \
              0, 0, 0);                                                       \
    __builtin_amdgcn_s_setprio(0); }

  // prologue: stage t0 -> buf0 (8), t1 -> buf1 (8); wait buf0; pre-read w0 ops
  stB(0, 0, 0, 0); stB(0, 0, 0, 1); stB(0, 0, 1, 0); stB(0, 0, 1, 1);
  stA(0, 0, 0); stA(0, 0, 1); stA(0, 0, 2); stA(0, 0, 3);
  stB(1, 1, 0, 0); stB(1, 1, 0, 1); stB(1, 1, 1, 0); stB(1, 1, 1, 1);
  stA(1, 1, 0); stA(1, 1, 1); stA(1, 1, 2); stA(1, 1, 3);
  asm volatile("s_waitcnt vmcnt(8)" ::: "memory");   // buf0 landed (this wave)
  asm volatile("s_barrier" ::: "memory");            // all waves' buf0 landed
  RDBALL(0, 0);
  RDAQ(0, 0, 1);

  for (int t = 0; t < NT; t += 2) {
    const int t2 = (t + 2 < NT) ? t + 2 : 0;   // wrap: valid mem, never MFMA'd
    const int t3 = (t + 3 < NT) ? t + 3 : 0;
    // w0: reads q1(buf0); stage B(t2)h0; MFMA Q0 buf0
    RDAQ(0, 1, 0);
    stB(0, t2, 0, 0); stB(0, t2, 0, 1);
    MFMA16(0, 1, 0);
    // w1
    RDAQ(0, 2, 1);
    stB(0, t2, 1, 0); stB(0, t2, 1, 1);
    MFMA16(1, 0, 0);
    // w2
    RDAQ(0, 3, 0);
    stA(0, t2, 0); stA(0, t2, 1);
    MFMA16(2, 1, 0);
    // w3: buf1 fully landed (vmcnt) -> pre-read its B + q0
    asm volatile("s_waitcnt vmcnt(6)" ::: "memory");
    RDBALL(1, 1);
    RDAQ(1, 0, 1);
    stA(0, t2, 2); stA(0, t2, 3);
    MFMA16(3, 0, 0);
    // w4
    RDAQ(1, 1, 0);
    stB(1, t3, 0, 0); stB(1, t3, 0, 1);
    MFMA16(0, 1, 1);
    // w5
    RDAQ(1, 2, 1);
    stB(1, t3, 1, 0); stB(1, t3, 1, 1);
    MFMA16(1, 0, 1);
    // w6
    RDAQ(1, 3, 0);
    stA(1, t3, 0); stA(1, t3, 1);
    MFMA16(2, 1, 1);
    // w7: buf0(t2) fully landed -> pre-read its B + q0
    asm volatile("s_waitcnt vmcnt(6)" ::: "memory");
    RDBALL(0, 0);
    RDAQ(0, 0, 1);
    stA(1, t3, 2); stA(1, t3, 3);
    MFMA16(3, 0, 1);
  }
#undef RDAQ
#undef RDBALL
#undef MFMA16

  asm volatile("s_waitcnt vmcnt(0)" ::: "memory");   // drain tail stages
  // epilogue: C/D layout col=lane&15, row=(lane>>4)*4+q
  float*  C  = (float*) Cv + (size_t)zz * M * N;
  ushort* Cb = (ushort*)Cv + (size_t)zz * M * N;
#pragma unroll
  for (int mi = 0; mi < 8; ++mi) {
    int row0 = m0 + wr * 128 + mi * 16 + kch * 4;
#pragma unroll
    for (int ni = 0; ni < 4; ++ni) {
      int col = n0 + wc * 64 + ni * 16 + lrow;
#pragma unroll
      for (int q_ = 0; q_ < 4; ++q_) {
        if (OUT == 0)
          C[(size_t)(row0 + q_) * N + col] = acc[mi][ni][q_];
        else
          Cb[(size_t)(row0 + q_) * N + col] = f2b(acc[mi][ni][q_]);
      }
    }
  }
}

// ---------------- 128x128 bf16 NT GEMM (narrow shapes) ----------------------
// EPI: 0 plain, 1 softplus(acc+bias). OBF: 0 f32 store, 1 bf16 store.
template <int EPI, int OBF>
__global__ __launch_bounds__(256) void gemm_nt(
    const ushort* __restrict__ A, const ushort* __restrict__ Bw,
    void* __restrict__ Cv, int M, int N, int ldk, int Kc,
    const float* __restrict__ bias) {
  __shared__ __align__(16) ushort As[128 * 64];
  __shared__ __align__(16) ushort Bs[128 * 64];
  const int tid  = threadIdx.x;
  const int lane = tid & 63;
  const int wid  = tid >> 6;
  const int wr = wid >> 1, wc = wid & 1;
  const int m0 = blockIdx.y * 128, n0 = blockIdx.x * 128;
  const int kbeg = blockIdx.z * Kc;
  float*  C  = (float*) Cv + (size_t)blockIdx.z * M * N;
  ushort* Cb = (ushort*)Cv + (size_t)blockIdx.z * M * N;
  const int rr0 = tid >> 3;
  const int sl  = tid & 7;
  const int lrow = lane & 15;
  const int lks  = lane >> 4;

  f32x4 acc[4][4] = {};

  for (int k0 = kbeg; k0 < kbeg + Kc; k0 += 64) {
#pragma unroll
    for (int i = 0; i < 4; ++i) {
      int rr  = i * 32 + rr0;
      int ksl = sl ^ (rr & 7);
      const ushort* ga = A  + (size_t)(m0 + rr) * ldk + k0 + ksl * 8;
      const ushort* gb = Bw + (size_t)(n0 + rr) * ldk + k0 + ksl * 8;
      ushort* la = As + (i * 256 + (wid << 6)) * 8;
      ushort* lb = Bs + (i * 256 + (wid << 6)) * 8;
      gload_lds16(ga, la);
      gload_lds16(gb, lb);
    }
    __syncthreads();
#pragma unroll
    for (int kc = 0; kc < 2; ++kc) {
      bf16x8 av[4], bv[4];
#pragma unroll
      for (int mi = 0; mi < 4; ++mi) {
        int row = wr * 64 + mi * 16 + lrow;
        int ks  = kc * 4 + lks;
        av[mi] = *(const bf16x8*)(As + row * 64 + ((ks ^ (row & 7)) << 3));
      }
#pragma unroll
      for (int ni = 0; ni < 4; ++ni) {
        int row = wc * 64 + ni * 16 + lrow;
        int ks  = kc * 4 + lks;
        bv[ni] = *(const bf16x8*)(Bs + row * 64 + ((ks ^ (row & 7)) << 3));
      }
#pragma unroll
      for (int mi = 0; mi < 4; ++mi)
#pragma unroll
        for (int ni = 0; ni < 4; ++ni)
          acc[mi][ni] = __builtin_amdgcn_mfma_f32_16x16x32_bf16(
              av[mi], bv[ni], acc[mi][ni], 0, 0, 0);
    }
    __syncthreads();
  }

#pragma unroll
  for (int mi = 0; mi < 4; ++mi) {
    int row0 = m0 + wr * 64 + mi * 16 + (lks << 2);
#pragma unroll
    for (int ni = 0; ni < 4; ++ni) {
      int col = n0 + wc * 64 + ni * 16 + lrow;
      float bcol = 0.f;
      if (EPI == 1) bcol = bias[col];
#pragma unroll
      for (int q = 0; q < 4; ++q) {
        float v = acc[mi][ni][q];
        if (EPI == 1) {
          v += bcol;
          v = (v > 20.f) ? v : log1pf(__expf(v));
        }
        if (OBF == 0) C [(size_t)(row0 + q) * N + col] = v;
        else          Cb[(size_t)(row0 + q) * N + col] = f2b(v);
      }
    }
  }
}

// ---------------- split-K reduce (out_proj) ---------------------------------
__global__ __launch_bounds__(256) void reduce2_kernel(
    const float* __restrict__ Cp, float* __restrict__ out) {
  size_t i = (size_t)blockIdx.x * 256 + threadIdx.x;
  const size_t MN4 = (size_t)LSEQ * HDIM / 4;
  float4 a = ((const float4*)Cp)[i];
  float4 b = ((const float4*)Cp)[MN4 + i];
  ((float4*)out)[i] = make_float4(a.x + b.x, a.y + b.y, a.z + b.z, a.w + b.w);
}

// ---------------- causal depthwise conv1d (K=4) + bias + SiLU --------------
// sliding window: block owns 256 d-channels x 16 l's; each u read once.
__global__ __launch_bounds__(256) void conv_silu_kernel(
    const ushort* __restrict__ ub, const float* __restrict__ cw,
    const float* __restrict__ cb, ushort* __restrict__ uc) {
  int d = blockIdx.x * 256 + threadIdx.x;
  int l0 = blockIdx.y * 16;
  float4 w4 = ((const float4*)cw)[d];
  float bsum = cb[d];
  float xm3 = (l0 >= 3) ? b2f(ub[(size_t)(l0 - 3) * DDIM + d]) : 0.f;
  float xm2 = (l0 >= 2) ? b2f(ub[(size_t)(l0 - 2) * DDIM + d]) : 0.f;
  float xm1 = (l0 >= 1) ? b2f(ub[(size_t)(l0 - 1) * DDIM + d]) : 0.f;
#pragma unroll
  for (int i = 0; i < 16; ++i) {
    int l = l0 + i;
    float xc = b2f(ub[(size_t)l * DDIM + d]);
    float s = bsum + w4.x * xm3 + w4.y * xm2 + w4.z * xm1 + w4.w * xc;
    float o = s / (1.f + __expf(-s));
    uc[(size_t)l * DDIM + d] = f2b(o);
    xm3 = xm2; xm2 = xm1; xm1 = xc;
  }
}

// ---------------- fused split-K reduce + RMSNorms ---------------------------
// Cp: 8 x [2048,384] partials. Per-l block of 64 lanes.
__global__ __launch_bounds__(64) void norms_kernel(
    const float* __restrict__ Cp, const float* __restrict__ dtw,
    const float* __restrict__ bw, const float* __restrict__ cwn,
    ushort* __restrict__ dtn, float* __restrict__ Bn, float* __restrict__ Cn) {
  int l = blockIdx.x, lane = threadIdx.x;
  const size_t MN = (size_t)LSEQ * NPAD;
  const float* row = Cp + (size_t)l * NPAD;
  float va[4] = {0.f, 0.f, 0.f, 0.f};
#pragma unroll
  for (int z = 0; z < 8; ++z) {
    float4 v = ((const float4*)(row + z * MN))[lane];
    va[0] += v.x; va[1] += v.y; va[2] += v.z; va[3] += v.w;
  }
  float ss = va[0]*va[0] + va[1]*va[1] + va[2]*va[2] + va[3]*va[3];
#pragma unroll
  for (int m = 32; m >= 1; m >>= 1) ss += __shfl_xor(ss, m);
  float rs = rsqrtf(ss * (1.f / 256.f) + 1e-6f);
  float4 wv = ((const float4*)dtw)[lane];
  float wa[4] = {wv.x, wv.y, wv.z, wv.w};
  union { ushort us[4]; uint2 v2; } o;
#pragma unroll
  for (int jj = 0; jj < 4; ++jj) o.us[jj] = f2b(va[jj] * rs * wa[jj]);
  ((uint2*)(dtn + (size_t)l * 256))[lane] = o.v2;

  int g = lane & 15;
  float bv = 0.f, cv = 0.f;
#pragma unroll
  for (int z = 0; z < 8; ++z) {
    bv += row[z * MN + 256 + g];
    cv += row[z * MN + 272 + g];
  }
  float bs = bv * bv, cs = cv * cv;
#pragma unroll
  for (int m = 8; m >= 1; m >>= 1) {
    bs += __shfl_xor(bs, m);
    cs += __shfl_xor(cs, m);
  }
  if (lane < 16) {
    Bn[(size_t)l * NST + lane] = bv * rsqrtf(bs * (1.f / 16.f) + 1e-6f) * bw[lane];
    Cn[(size_t)l * NST + lane] = cv * rsqrtf(cs * (1.f / 16.f) + 1e-6f) * cwn[lane];
  }
}

// ---------------- selective scan, chunked over L ----------------------------
__global__ __launch_bounds__(256) void scan_phase1(
    const ushort* __restrict__ delta, const ushort* __restrict__ uc,
    const float* __restrict__ Bn, const float* __restrict__ Am,
    float* __restrict__ Sbuf, float* __restrict__ Pbuf) {
  __shared__ float sB[CLEN * NST];
  const int tid = threadIdx.x;
  const int d = blockIdx.x * 256 + tid;
  const int c = blockIdx.y, l0 = c * CLEN;
  {
    const float4* bsrc = (const float4*)(Bn + (size_t)l0 * NST);
    float4* bdst = (float4*)sB;
    for (int i = tid; i < CLEN * NST / 4; i += 256) bdst[i] = bsrc[i];
  }
  __syncthreads();
  float A[16];
#pragma unroll
  for (int jj = 0; jj < 4; ++jj) {
    float4 a4 = ((const float4*)(Am + (size_t)d * NST))[jj];
    A[4*jj] = a4.x; A[4*jj+1] = a4.y; A[4*jj+2] = a4.z; A[4*jj+3] = a4.w;
  }
  float st[16] = {};
  float sd = 0.f;
  const size_t base = (size_t)l0 * DDIM + d;
  float dx0 = b2f(delta[base]),  dx1 = b2f(delta[base + DDIM]);
  float ux0 = b2f(uc[base]),     ux1 = b2f(uc[base + DDIM]);
  for (int l = 0; l < CLEN; l += 2) {
    int lp = (l + 2 < CLEN) ? l + 2 : CLEN - 2;
    float dxn0 = b2f(delta[base + (size_t)lp * DDIM]);
    float dxn1 = b2f(delta[base + (size_t)(lp + 1) * DDIM]);
    float uxn0 = b2f(uc[base + (size_t)lp * DDIM]);
    float uxn1 = b2f(uc[base + (size_t)(lp + 1) * DDIM]);
    sd += dx0;
    float dxu = dx0 * ux0;
#pragma unroll
    for (int n = 0; n < 16; ++n)
      st[n] = fmaf(__expf(dx0 * A[n]), st[n], dxu * sB[l * NST + n]);
    sd += dx1;
    dxu = dx1 * ux1;
#pragma unroll
    for (int n = 0; n < 16; ++n)
      st[n] = fmaf(__expf(dx1 * A[n]), st[n], dxu * sB[(l + 1) * NST + n]);
    dx0 = dxn0; dx1 = dxn1; ux0 = uxn0; ux1 = uxn1;
  }
  float4* Sd = (float4*)(Sbuf + ((size_t)c * DDIM + d) * NST);
  float4* Pd = (float4*)(Pbuf + ((size_t)c * DDIM + d) * NST);
#pragma unroll
  for (int jj = 0; jj < 4; ++jj) {
    Sd[jj] = make_float4(st[4*jj], st[4*jj+1], st[4*jj+2], st[4*jj+3]);
    Pd[jj] = make_float4(__expf(A[4*jj] * sd),   __expf(A[4*jj+1] * sd),
                         __expf(A[4*jj+2] * sd), __expf(A[4*jj+3] * sd));
  }
}

__global__ __launch_bounds__(256) void scan_phase2(
    const float* __restrict__ Sbuf, float* __restrict__ Pbuf) {
  size_t t = (size_t)blockIdx.x * 256 + threadIdx.x;
  const size_t stride = (size_t)DDIM * NST;
  float s = 0.f;
  for (int c = 0; c < NC; ++c) {
    float P = Pbuf[c * stride + t];
    float S = Sbuf[c * stride + t];
    Pbuf[c * stride + t] = s;
    s = fmaf(P, s, S);
  }
}

__global__ __launch_bounds__(256) void scan_phase3(
    const ushort* __restrict__ delta, const ushort* __restrict__ uc,
    const float* __restrict__ Bn, const float* __restrict__ Cn,
    const float* __restrict__ Am, const float* __restrict__ Ibuf,
    const ushort* __restrict__ gbuf, const float* __restrict__ Dp,
    ushort* __restrict__ yg) {
  __shared__ float sB[CLEN * NST];
  __shared__ float sC[CLEN * NST];
  const int tid = threadIdx.x;
  const int d = blockIdx.x * 256 + tid;
  const int c = blockIdx.y, l0 = c * CLEN;
  {
    const float4* bsrc = (const float4*)(Bn + (size_t)l0 * NST);
    const float4* csrc = (const float4*)(Cn + (size_t)l0 * NST);
    float4* bdst = (float4*)sB;
    float4* cdst = (float4*)sC;
    for (int i = tid; i < CLEN * NST / 4; i += 256) {
      bdst[i] = bsrc[i];
      cdst[i] = csrc[i];
    }
  }
  __syncthreads();
  float A[16], st[16];
#pragma unroll
  for (int jj = 0; jj < 4; ++jj) {
    float4 a4 = ((const float4*)(Am + (size_t)d * NST))[jj];
    A[4*jj] = a4.x; A[4*jj+1] = a4.y; A[4*jj+2] = a4.z; A[4*jj+3] = a4.w;
    float4 s4 = ((const float4*)(Ibuf + ((size_t)c * DDIM + d) * NST))[jj];
    st[4*jj] = s4.x; st[4*jj+1] = s4.y; st[4*jj+2] = s4.z; st[4*jj+3] = s4.w;
  }
  const float Dpd = Dp[d];
  const size_t base = (size_t)l0 * DDIM + d;
  float dx0 = b2f(delta[base]),   dx1 = b2f(delta[base + DDIM]);
  float ux0 = b2f(uc[base]),      ux1 = b2f(uc[base + DDIM]);
  float g0  = b2f(gbuf[base]),    g1  = b2f(gbuf[base + DDIM]);
  for (int l = 0; l < CLEN; l += 2) {
    int lp = (l + 2 < CLEN) ? l + 2 : CLEN - 2;
    float dxn0 = b2f(delta[base + (size_t)lp * DDIM]);
    float dxn1 = b2f(delta[base + (size_t)(lp + 1) * DDIM]);
    float uxn0 = b2f(uc[base + (size_t)lp * DDIM]);
    float uxn1 = b2f(uc[base + (size_t)(lp + 1) * DDIM]);
    float gn0  = b2f(gbuf[base + (size_t)lp * DDIM]);
    float gn1  = b2f(gbuf[base + (size_t)(lp + 1) * DDIM]);
    {
      float dxu = dx0 * ux0, y0 = 0.f, y1 = 0.f;
#pragma unroll
      for (int n = 0; n < 16; n += 2) {
        st[n]   = fmaf(__expf(dx0 * A[n]),   st[n],   dxu * sB[l * NST + n]);
        st[n+1] = fmaf(__expf(dx0 * A[n+1]), st[n+1], dxu * sB[l * NST + n+1]);
        y0 = fmaf(st[n],   sC[l * NST + n],   y0);
        y1 = fmaf(st[n+1], sC[l * NST + n+1], y1);
      }
      float o = (y0 + y1 + ux0 * Dpd) * (g0 / (1.f + __expf(-g0)));
      yg[base + (size_t)l * DDIM] = f2b(o);
    }
    {
      float dxu = dx1 * ux1, y0 = 0.f, y1 = 0.f;
#pragma unroll
      for (int n = 0; n < 16; n += 2) {
        st[n]   = fmaf(__expf(dx1 * A[n]),   st[n],   dxu * sB[(l+1) * NST + n]);
        st[n+1] = fmaf(__expf(dx1 * A[n+1]), st[n+1], dxu * sB[(l+1) * NST + n+1]);
        y0 = fmaf(st[n],   sC[(l+1) * NST + n],   y0);
        y1 = fmaf(st[n+1], sC[(l+1) * NST + n+1], y1);
      }
      float o = (y0 + y1 + ux1 * Dpd) * (g1 / (1.f + __expf(-g1)));
      yg[base + (size_t)(l + 1) * DDIM] = f2b(o);
    }
    dx0 = dxn0; dx1 = dxn1; ux0 = uxn0; ux1 = uxn1; g0 = gn0; g1 = gn1;
  }
}

// ---------------------------------------------------------------------------
extern "C" void kernel_launch(void* const* d_in, const int* in_sizes, int n_in,
                              void* d_out, int out_size, void* d_ws, size_t ws_size,
                              hipStream_t stream) {
  (void)in_sizes; (void)n_in; (void)out_size; (void)ws_size;
  const float* hs   = (const float*)d_in[0];
  const float* W_in = (const float*)d_in[1];
  const float* cw   = (const float*)d_in[2];
  const float* cb   = (const float*)d_in[3];
  const float* Wx   = (const float*)d_in[4];
  const float* dtw  = (const float*)d_in[5];
  const float* bw   = (const float*)d_in[6];
  const float* cwn  = (const float*)d_in[7];
  const float* Wdt  = (const float*)d_in[8];
  const float* dtb  = (const float*)d_in[9];
  const float* Am   = (const float*)d_in[10];
  const float* Dp   = (const float*)d_in[11];
  const float* Wout = (const float*)d_in[12];
  float* out = (float*)d_out;

  char* ws = (char*)d_ws;
  const size_t MB = 1ull << 20;
  // region A (128MB): win_b for in_proj; after: delta_b (32MB) + wout_b (64MB)
  ushort* win_b   = (ushort*)(ws);
  ushort* delta_b = (ushort*)(ws);
  ushort* wout_b  = (ushort*)(ws + 64 * MB);
  // region B: ubuf bf16 (32MB @128); after conv: Cp(24 @128)+Sbuf(8 @152)+
  //           Pbuf(8 @160); out_proj partials Cp2 (64 @128)
  ushort* ubuf   = (ushort*)(ws + 128 * MB);
  float*  Cp     = (float*) (ws + 128 * MB);
  float*  Cp2    = (float*) (ws + 128 * MB);
  float*  Sbuf   = (float*) (ws + 152 * MB);
  float*  Pbuf   = (float*) (ws + 160 * MB);
  ushort* gbuf   = (ushort*)(ws + 192 * MB);          // 32MB (bf16 gate)
  ushort* hs_b   = (ushort*)(ws + 256 * MB);          // 16MB
  ushort* wxp_b  = (ushort*)(ws + 272 * MB);          // 6MB
  ushort* wdt_b  = (ushort*)(ws + 278 * MB);          // 4MB
  ushort* ucv    = (ushort*)(ws + 282 * MB);          // 32MB
  ushort* dtn    = (ushort*)(ws + 317 * MB);          // 1MB
  float*  Bn     = (float*) (ws + 318 * MB);
  float*  Cn     = (float*) (ws + 318 * MB + 131072);
  ushort* yg     = (ushort*)(ws + 319 * MB);          // 32MB; end 351MB

  // f32 -> bf16 conversions
  cvt_kernel<<<67108864 / 2048, 256, 0, stream>>>(W_in, win_b, 67108864 / 8);
  cvt_kernel<<<8388608 / 2048, 256, 0, stream>>>(hs, hs_b, 8388608 / 8);
  cvt_kernel<<<2359296 / 2048, 256, 0, stream>>>(Wx, wxp_b, 2359296 / 8);
  hipMemsetAsync((char*)wxp_b + 4718592, 0, 1572864, stream);
  cvt_kernel<<<2097152 / 2048, 256, 0, stream>>>(Wdt, wdt_b, 2097152 / 8);

  // 1) in_proj (pipelined 8-window 256^2): u (bf16) and gate (bf16) halves
  gemm8p<0, 1><<<dim3(32, 8), 512, 0, stream>>>(hs_b, win_b, ubuf,
                                                2048, DDIM, 4096, 4096);
  gemm8p<0, 1><<<dim3(32, 8), 512, 0, stream>>>(hs_b, win_b + (size_t)DDIM * 4096,
                                                gbuf, 2048, DDIM, 4096, 4096);
  cvt_kernel<<<33554432 / 2048, 256, 0, stream>>>(Wout, wout_b, 33554432 / 8);

  // 2) causal conv + SiLU -> u_conv bf16 (sliding window, each u read once)
  conv_silu_kernel<<<dim3(32, 128), 256, 0, stream>>>(ubuf, cw, cb, ucv);

  // 3) x_proj, split-K x8 -> partials (reduce fused into norms)
  gemm_nt<0, 0><<<dim3(3, 16, 8), 256, 0, stream>>>(ucv, wxp_b, Cp,
                                                    2048, NPAD, 8192, 1024,
                                                    nullptr);
  // 4) fused reduce + RMSNorms
  norms_kernel<<<2048, 64, 0, stream>>>(Cp, dtw, bw, cwn, dtn, Bn, Cn);

  // 5) dt_proj + softplus -> delta bf16
  gemm_nt<1, 1><<<dim3(64, 16), 256, 0, stream>>>(dtn, wdt_b, delta_b,
                                                  2048, DDIM, 256, 256, dtb);

  // 6) chunked selective scan; phase3 fuses skip+gate -> yg bf16
  scan_phase1<<<dim3(32, NC), 256, 0, stream>>>(delta_b, ucv, Bn, Am, Sbuf, Pbuf);
  scan_phase2<<<512, 256, 0, stream>>>(Sbuf, Pbuf);
  scan_phase3<<<dim3(32, NC), 256, 0, stream>>>(delta_b, ucv, Bn, Cn, Am, Pbuf,
                                                gbuf, Dp, yg);

  // 7) out_proj (pipelined, 4m4n2z XCD chunks, split-K x2) -> reduce
  gemm8p<1, 0><<<dim3(16, 8, 2), 512, 0, stream>>>(yg, wout_b, Cp2,
                                                   2048, HDIM, 8192, 4096);
  reduce2_kernel<<<(LSEQ * HDIM / 4) / 256, 256, 0, stream>>>(Cp2, out);
}